// Round 1
// baseline (1571.534 us; speedup 1.0000x reference)
//
#include <hip/hip_runtime.h>

// ---------------------------------------------------------------------------
// TAOBAODurendal: 2-layer hetero GraphConv + temporal blend + link scoring.
// Round-4 design (on top of round-3):
//  * NEW: bf16 shadow tables for all gathered features. The MFMA pipeline
//    already rounds feats to bf16, so gathering f32 wastes half the bytes.
//    x_user/x_item are converted once; layer-1 outputs write a bf16 shadow
//    in the epilogue (in addition to the f32 d_out copy). Halves the ~2 GB
//    of random row-gather traffic and halves loads/edge; 2x edge-loop unroll
//    for memory-level parallelism. Falls back to the verified f32-gather
//    path if ws_size is too small for the shadows (~88 MB needed).
//  * Inputs AND outputs are f32 (per reference); on-device probe confirms and
//    keeps a bf16 fallback path. Output carve uses element offsets.
//  * CSR build per launch (hist -> scan -> bucket), reused by both layers.
//  * seg-mean fused into the MFMA GEMM as a per-row gather loop.
//  * _sem_agg with R=1 is identity; Wp folded into relation weights;
//    link score collapses to dot(u*i, Wpost[:,0]+Wpost[:,1]) + sum(bpost).
// ---------------------------------------------------------------------------

#define NUSER 100000
#define NITEM 50000
#define CDIM  128
#define EDGES 1000000
#define LBL   200000

// element offsets inside d_out: [h | cur1_user | cur1_item | cur2_user | cur2_item]
#define OFF_C1U ((long)LBL)
#define OFF_C1I (OFF_C1U + (long)NUSER * CDIM)
#define OFF_C2U (OFF_C1I + (long)NITEM * CDIM)
#define OFF_C2I (OFF_C2U + (long)NUSER * CDIM)

typedef __bf16 bf16x8 __attribute__((ext_vector_type(8)));
typedef float  f32x4  __attribute__((ext_vector_type(4)));

// ---- dual-dtype scalar load -------------------------------------------------
__device__ __forceinline__ float ld1(const void* base, size_t idx, bool isf32) {
  return isf32 ? ((const float*)base)[idx] : (float)((const __bf16*)base)[idx];
}

// ---- dtype probe ------------------------------------------------------------
// f32 data: even 16-bit halves are random mantissa bits -> ~48%/sample show
// bf16-exponent > 0x85 (|v|>64). bf16 N(0,1) data never does. flag=1 for f32.
__global__ void probe_dtype_kernel(const unsigned short* __restrict__ x,
                                   int* __restrict__ flag) {
  int t = threadIdx.x;  // 256
  int bad = 0;
  for (int i = t * 2; i < 8192; i += 512) {
    int e = (x[i] >> 7) & 0xFF;
    if (e > 0x85) bad = 1;
  }
  if (bad) atomicOr(flag, 1);
}

// ---- CSR build --------------------------------------------------------------
__global__ __launch_bounds__(256) void hist_kernel(
    const int* __restrict__ dst_ui, const int* __restrict__ dst_iu,
    int* __restrict__ cntI, int* __restrict__ cntU) {
  int e = blockIdx.x * 256 + threadIdx.x;
  if (e < EDGES) {
    atomicAdd(&cntI[dst_ui[e]], 1);
    atomicAdd(&cntU[dst_iu[e]], 1);
  }
}

// single-block exclusive scan, writes off[0..n] and cur=off.
__global__ __launch_bounds__(1024) void scan_kernel(const int* __restrict__ cnt,
                                                    int* __restrict__ off,
                                                    int* __restrict__ cur,
                                                    int n) {
  __shared__ int wsums[16];
  __shared__ int carry_s;
  int t = threadIdx.x, lane = t & 63, w = t >> 6;
  if (t == 0) carry_s = 0;
  __syncthreads();
  for (int base = 0; base < n; base += 1024) {
    int i = base + t;
    int v = (i < n) ? cnt[i] : 0;
    int x = v;
#pragma unroll
    for (int s = 1; s < 64; s <<= 1) {
      int y = __shfl_up(x, s, 64);
      if (lane >= s) x += y;
    }
    if (lane == 63) wsums[w] = x;
    __syncthreads();
    int woff = 0;
    for (int ww = 0; ww < w; ++ww) woff += wsums[ww];
    int carry = carry_s;
    __syncthreads();
    int excl = carry + woff + x - v;
    if (i < n) { off[i] = excl; cur[i] = excl; }
    if (t == 1023) carry_s = excl + v;
    __syncthreads();
  }
  if (t == 0) off[n] = carry_s;
}

__global__ __launch_bounds__(256) void bucket_kernel(
    const int* __restrict__ src_ui, const int* __restrict__ dst_ui,
    const int* __restrict__ src_iu, const int* __restrict__ dst_iu,
    int* __restrict__ curI, int* __restrict__ curU,
    int* __restrict__ permI, int* __restrict__ permU) {
  int e = blockIdx.x * 256 + threadIdx.x;
  if (e < EDGES) {
    int p = atomicAdd(&curI[dst_ui[e]], 1);
    permI[p] = src_ui[e];
    int p2 = atomicAdd(&curU[dst_iu[e]], 1);
    permU[p2] = src_iu[e];
  }
}

// ---- bf16 shadow conversion -------------------------------------------------
// 8 elems/thread; n must be a multiple of 8.
__global__ __launch_bounds__(256) void convert_bf16_kernel(
    const void* __restrict__ in, __bf16* __restrict__ outp, long n,
    const int* __restrict__ flag) {
  bool f = flag[0] != 0;
  long i = ((long)blockIdx.x * 256 + threadIdx.x) * 8;
  if (i + 8 > n) return;
  bf16x8 o;
  if (f) {
    f32x4 a = *(const f32x4*)((const float*)in + i);
    f32x4 b = *(const f32x4*)((const float*)in + i + 4);
#pragma unroll
    for (int j = 0; j < 4; ++j) {
      o[j] = (__bf16)a[j];
      o[4 + j] = (__bf16)b[j];
    }
  } else {
    o = *(const bf16x8*)((const __bf16*)in + i);
  }
  *(bf16x8*)(outp + i) = o;
}

// ---- weight prep ------------------------------------------------------------
__global__ __launch_bounds__(128) void prep_transpose_kernel(
    const void* __restrict__ W0, const void* __restrict__ W1,
    const void* __restrict__ W2, const void* __restrict__ W3,
    __bf16* __restrict__ T0, __bf16* __restrict__ T1,
    __bf16* __restrict__ T2, __bf16* __restrict__ T3,
    const int* __restrict__ flag) {
  bool f = flag[0] != 0;
  int k = blockIdx.x, n = threadIdx.x, y = blockIdx.y;
  const void* W = (y == 0) ? W0 : (y == 1) ? W1 : (y == 2) ? W2 : W3;
  __bf16* T = (y == 0) ? T0 : (y == 1) ? T1 : (y == 2) ? T2 : T3;
  T[n * CDIM + k] = (__bf16)ld1(W, (size_t)k * CDIM + n, f);
}

// Tt = (W @ Wp)^T, f32 accumulate, bf16 store.
__global__ __launch_bounds__(128) void prep_combine_kernel(
    const void* __restrict__ W0, const void* __restrict__ W1,
    const void* __restrict__ W2, const void* __restrict__ W3,
    const void* __restrict__ Wp1, const void* __restrict__ Wp2,
    __bf16* __restrict__ T0, __bf16* __restrict__ T1,
    __bf16* __restrict__ T2, __bf16* __restrict__ T3,
    const int* __restrict__ flag) {
  bool f = flag[0] != 0;
  int k = blockIdx.x, n = threadIdx.x, y = blockIdx.y;
  const void* W = (y == 0) ? W0 : (y == 1) ? W1 : (y == 2) ? W2 : W3;
  const void* Wp = (y < 2) ? Wp1 : Wp2;
  __bf16* T = (y == 0) ? T0 : (y == 1) ? T1 : (y == 2) ? T2 : T3;
  float s = 0.f;
#pragma unroll 4
  for (int j = 0; j < CDIM; ++j)
    s += ld1(W, (size_t)k * CDIM + j, f) * ld1(Wp, (size_t)j * CDIM + n, f);
  T[n * CDIM + k] = (__bf16)s;
}

__global__ void prep_misc_kernel(const void* __restrict__ Wpost,
                                 const void* __restrict__ bpost,
                                 const void* __restrict__ bp1,
                                 const void* __restrict__ bp2,
                                 float* __restrict__ wsum,
                                 float* __restrict__ bpf1,
                                 float* __restrict__ bpf2,
                                 const int* __restrict__ flag) {
  bool f = flag[0] != 0;
  int t = threadIdx.x;  // 128
  wsum[t] = ld1(Wpost, (size_t)t * 2, f) + ld1(Wpost, (size_t)t * 2 + 1, f);
  bpf1[t] = ld1(bp1, t, f);
  bpf2[t] = ld1(bp2, t, f);
  if (t == 0) wsum[CDIM] = ld1(bpost, 0, f) + ld1(bpost, 1, f);
}

// ---- fused gather(seg-mean) + dual-GEMM + bias + temporal blend -------------
// out = blend(past, mean_{CSR}(feat) @ WtN^T + X @ WtS^T + bias).
// One wave per 16-row tile. mfma_f32_16x16x32_bf16 layouts:
//   A: lane = A[m=lane&15][k=(lane>>4)*8+j]; B: lane = B[k=(lane>>4)*8+j][n=lane&15]
//   (Wt[n][k] storage); C/D: col=lane&15, row=(lane>>4)*4+reg (m89/m91-verified).
// SHADOW mode: featb/Xb are bf16 shadow tables (halved gather bytes, 2x
// unrolled edge loop); optional bf16 shadow_out mirrors the d_out write.
// Non-shadow mode is the previously-verified dual-dtype path.
template <bool HAS_BIAS, bool SHADOW>
__global__ __launch_bounds__(256) void gather_gemm_kernel(
    const int* __restrict__ off, const int* __restrict__ perm,
    const void* __restrict__ featb, long featoff,
    const void* __restrict__ Xb, long xoff,
    const __bf16* __restrict__ WtN, const __bf16* __restrict__ WtS,
    const float* __restrict__ bias, const void* __restrict__ past,
    __bf16* __restrict__ shadow_out,
    const int* __restrict__ snapp, const int* __restrict__ flag,
    void* __restrict__ outb, long outoff, int nRowTiles) {
  bool f32 = (flag[0] != 0);
  bool blend = (snapp[0] != 0);
  int lane = threadIdx.x & 63;
  int ln = lane & 15, q = lane >> 4;
  int wave = blockIdx.x * 4 + (threadIdx.x >> 6);
  int nW = gridDim.x * 4;
  size_t cq = (size_t)q * 8;
  for (int rt = wave; rt < nRowTiles; rt += nW) {
    int row = rt * 16 + ln;
    int beg = off[row], end = off[row + 1];
    float s[4][8];
#pragma unroll
    for (int a = 0; a < 4; ++a)
#pragma unroll
      for (int j = 0; j < 8; ++j) s[a][j] = 0.f;
    if (SHADOW) {
      const __bf16* fb = (const __bf16*)featb + cq;
      int i = beg;
      for (; i + 1 < end; i += 2) {
        const __bf16* fp0 = fb + (size_t)perm[i] * CDIM;
        const __bf16* fp1 = fb + (size_t)perm[i + 1] * CDIM;
        bf16x8 v0[4], v1[4];
#pragma unroll
        for (int ks = 0; ks < 4; ++ks) v0[ks] = *(const bf16x8*)(fp0 + ks * 32);
#pragma unroll
        for (int ks = 0; ks < 4; ++ks) v1[ks] = *(const bf16x8*)(fp1 + ks * 32);
#pragma unroll
        for (int ks = 0; ks < 4; ++ks)
#pragma unroll
          for (int j = 0; j < 8; ++j)
            s[ks][j] += (float)v0[ks][j] + (float)v1[ks][j];
      }
      if (i < end) {
        const __bf16* fp = fb + (size_t)perm[i] * CDIM;
#pragma unroll
        for (int ks = 0; ks < 4; ++ks) {
          bf16x8 v = *(const bf16x8*)(fp + ks * 32);
#pragma unroll
          for (int j = 0; j < 8; ++j) s[ks][j] += (float)v[j];
        }
      }
    } else if (f32) {
      const float* fb = (const float*)featb + featoff + cq;
      for (int i = beg; i < end; ++i) {
        const float* fp = fb + (size_t)perm[i] * CDIM;
#pragma unroll
        for (int ks = 0; ks < 4; ++ks) {
          f32x4 lo = *(const f32x4*)(fp + ks * 32);
          f32x4 hi = *(const f32x4*)(fp + ks * 32 + 4);
#pragma unroll
          for (int j = 0; j < 4; ++j) {
            s[ks][j] += lo[j];
            s[ks][4 + j] += hi[j];
          }
        }
      }
    } else {
      const __bf16* fb = (const __bf16*)featb + featoff + cq;
      for (int i = beg; i < end; ++i) {
        const __bf16* fp = fb + (size_t)perm[i] * CDIM;
#pragma unroll
        for (int ks = 0; ks < 4; ++ks) {
          bf16x8 v = *(const bf16x8*)(fp + ks * 32);
#pragma unroll
          for (int j = 0; j < 8; ++j) s[ks][j] += (float)v[j];
        }
      }
    }
    float rc = 1.0f / fmaxf((float)(end - beg), 1.0f);
    bf16x8 a1[4], a2[4];
    size_t xb = (size_t)row * CDIM + cq;
#pragma unroll
    for (int ks = 0; ks < 4; ++ks) {
      bf16x8 t1, t2;
      if (SHADOW) {
        t2 = *(const bf16x8*)((const __bf16*)Xb + xb + ks * 32);
      } else if (f32) {
        const float* xp = (const float*)Xb + xoff + xb + ks * 32;
        f32x4 lo = *(const f32x4*)xp;
        f32x4 hi = *(const f32x4*)(xp + 4);
#pragma unroll
        for (int j = 0; j < 4; ++j) {
          t2[j] = (__bf16)lo[j];
          t2[4 + j] = (__bf16)hi[j];
        }
      } else {
        t2 = *(const bf16x8*)((const __bf16*)Xb + xoff + xb + ks * 32);
      }
#pragma unroll
      for (int j = 0; j < 8; ++j) t1[j] = (__bf16)(s[ks][j] * rc);
      a1[ks] = t1;
      a2[ks] = t2;
    }
    f32x4 d[8];
#pragma unroll
    for (int ct = 0; ct < 8; ++ct) d[ct] = (f32x4){0.f, 0.f, 0.f, 0.f};
#pragma unroll
    for (int ct = 0; ct < 8; ++ct) {
      const __bf16* bn = WtN + (size_t)(ct * 16 + ln) * CDIM + q * 8;
      const __bf16* bs = WtS + (size_t)(ct * 16 + ln) * CDIM + q * 8;
#pragma unroll
      for (int ks = 0; ks < 4; ++ks) {
        d[ct] = __builtin_amdgcn_mfma_f32_16x16x32_bf16(
            a1[ks], *(const bf16x8*)(bn + ks * 32), d[ct], 0, 0, 0);
        d[ct] = __builtin_amdgcn_mfma_f32_16x16x32_bf16(
            a2[ks], *(const bf16x8*)(bs + ks * 32), d[ct], 0, 0, 0);
      }
    }
#pragma unroll
    for (int ct = 0; ct < 8; ++ct) {
      int col = ct * 16 + ln;
      float bv = HAS_BIAS ? bias[col] : 0.0f;
#pragma unroll
      for (int r = 0; r < 4; ++r) {
        long orow = rt * 16 + q * 4 + r;
        float v = d[ct][r] + bv;
        if (blend)
          v = 0.05f * ld1(past, (size_t)orow * CDIM + col, f32) + 0.95f * v;
        if (SHADOW) {
          if (shadow_out)
            shadow_out[(size_t)orow * CDIM + col] = (__bf16)v;
        }
        size_t oidx = (size_t)(outoff + orow * CDIM + col);
        if (f32)
          ((float*)outb)[oidx] = v;
        else
          ((__bf16*)outb)[oidx] = (__bf16)v;
      }
    }
  }
}

// ---- link scoring -----------------------------------------------------------
// h[l] = dot(u2[ls]*i2[ld], wsum) + bsum.  16 lanes per label, 8 ch each.
__global__ __launch_bounds__(256) void score_kernel(
    void* __restrict__ outb, const int* __restrict__ ls,
    const int* __restrict__ ld, const float* __restrict__ wsum,
    const int* __restrict__ flag) {
  bool f32 = (flag[0] != 0);
  int t = blockIdx.x * blockDim.x + threadIdx.x;
  int l = t >> 4;
  if (l >= LBL) return;
  size_t c8 = (size_t)(t & 15) << 3;
  float av[8], bv[8];
  if (f32) {
    const float* u = (const float*)outb + OFF_C2U + (size_t)ls[l] * CDIM + c8;
    const float* v = (const float*)outb + OFF_C2I + (size_t)ld[l] * CDIM + c8;
    f32x4 u0 = *(const f32x4*)u, u1 = *(const f32x4*)(u + 4);
    f32x4 v0 = *(const f32x4*)v, v1 = *(const f32x4*)(v + 4);
#pragma unroll
    for (int j = 0; j < 4; ++j) {
      av[j] = u0[j]; av[4 + j] = u1[j];
      bv[j] = v0[j]; bv[4 + j] = v1[j];
    }
  } else {
    bf16x8 a = *(const bf16x8*)((const __bf16*)outb + OFF_C2U +
                                (size_t)ls[l] * CDIM + c8);
    bf16x8 b = *(const bf16x8*)((const __bf16*)outb + OFF_C2I +
                                (size_t)ld[l] * CDIM + c8);
#pragma unroll
    for (int j = 0; j < 8; ++j) { av[j] = (float)a[j]; bv[j] = (float)b[j]; }
  }
  float p = 0.f;
#pragma unroll
  for (int j = 0; j < 8; ++j) p += av[j] * bv[j] * wsum[c8 + j];
  p += __shfl_xor(p, 1, 16);
  p += __shfl_xor(p, 2, 16);
  p += __shfl_xor(p, 4, 16);
  p += __shfl_xor(p, 8, 16);
  if ((t & 15) == 0) {
    float h = p + wsum[CDIM];
    if (f32)
      ((float*)outb)[l] = h;
    else
      ((__bf16*)outb)[l] = (__bf16)h;
  }
}

// ---------------------------------------------------------------------------
extern "C" void kernel_launch(void* const* d_in, const int* in_sizes, int n_in,
                              void* d_out, int out_size, void* d_ws,
                              size_t ws_size, hipStream_t stream) {
  const void* x_user = d_in[0];
  const void* x_item = d_in[1];
  const void* past1_user = d_in[2];
  const void* past1_item = d_in[3];
  const void* past2_user = d_in[4];
  const void* past2_item = d_in[5];
  const void* W1ui_n = d_in[6];
  const void* W1ui_s = d_in[7];
  const void* W1iu_n = d_in[8];
  const void* W1iu_s = d_in[9];
  const void* Wp1 = d_in[10];
  const void* bp1 = d_in[11];
  const void* W2ui_n = d_in[15];
  const void* W2ui_s = d_in[16];
  const void* W2iu_n = d_in[17];
  const void* W2iu_s = d_in[18];
  const void* Wp2 = d_in[19];
  const void* bp2 = d_in[20];
  const void* Wpost = d_in[24];
  const void* bpost = d_in[25];
  const int* src_ui = (const int*)d_in[26];
  const int* dst_ui = (const int*)d_in[27];
  const int* src_iu = (const int*)d_in[28];
  const int* dst_iu = (const int*)d_in[29];
  const int* lbl_src = (const int*)d_in[30];
  const int* lbl_dst = (const int*)d_in[31];
  const int* snap = (const int*)d_in[32];

  // ---- workspace carve, 256B-aligned sections ----
  size_t wo = 0;
  auto alloc = [&](size_t bytes) -> char* {
    char* p = (char*)d_ws + wo;
    wo += (bytes + 255) & ~(size_t)255;
    return p;
  };
  int* cntI = (int*)alloc(NITEM * 4);
  int* cntU = (int*)alloc(NUSER * 4);
  int* flag = (int*)alloc(256);
  size_t zeroBytes = wo;  // cntI + cntU + flag zeroed in one memset
  int* offI = (int*)alloc((NITEM + 1) * 4);
  int* offU = (int*)alloc((NUSER + 1) * 4);
  int* curI = (int*)alloc(NITEM * 4);
  int* curU = (int*)alloc(NUSER * 4);
  int* permI = (int*)alloc(EDGES * 4);
  int* permU = (int*)alloc(EDGES * 4);
  float* wsum = (float*)alloc(256 * 4);
  float* bpf1 = (float*)alloc(CDIM * 4);
  float* bpf2 = (float*)alloc(CDIM * 4);
  __bf16* wt0 = (__bf16*)alloc(8 * CDIM * CDIM * 2);
  __bf16* Wt[8];
  for (int i = 0; i < 8; ++i) Wt[i] = wt0 + (size_t)i * CDIM * CDIM;
  // bf16 shadow tables (gather sources). Allocated last; used only if they fit.
  __bf16* xu_sh = (__bf16*)alloc((size_t)NUSER * CDIM * 2);
  __bf16* xi_sh = (__bf16*)alloc((size_t)NITEM * CDIM * 2);
  __bf16* c1u_sh = (__bf16*)alloc((size_t)NUSER * CDIM * 2);
  __bf16* c1i_sh = (__bf16*)alloc((size_t)NITEM * CDIM * 2);
  bool useShadow = (wo <= ws_size);

  const int EB = (EDGES + 255) / 256;
  const int G_ITEM = (NITEM / 16 + 3) / 4;
  const int G_USER = (NUSER / 16 + 3) / 4;

  hipMemsetAsync(d_ws, 0, zeroBytes, stream);
  probe_dtype_kernel<<<1, 256, 0, stream>>>((const unsigned short*)x_user,
                                            flag);

  // CSR build (shared by both layers)
  hist_kernel<<<EB, 256, 0, stream>>>(dst_ui, dst_iu, cntI, cntU);
  scan_kernel<<<1, 1024, 0, stream>>>(cntI, offI, curI, NITEM);
  scan_kernel<<<1, 1024, 0, stream>>>(cntU, offU, curU, NUSER);
  bucket_kernel<<<EB, 256, 0, stream>>>(src_ui, dst_ui, src_iu, dst_iu, curI,
                                        curU, permI, permU);

  // weight prep: Wt0/1 = W1ui_{n,s}^T, Wt4/5 = W2ui_{n,s}^T,
  //              Wt2/3 = (W1iu_{n,s}@Wp1)^T, Wt6/7 = (W2iu_{n,s}@Wp2)^T
  prep_transpose_kernel<<<dim3(CDIM, 4), CDIM, 0, stream>>>(
      W1ui_n, W1ui_s, W2ui_n, W2ui_s, Wt[0], Wt[1], Wt[4], Wt[5], flag);
  prep_combine_kernel<<<dim3(CDIM, 4), CDIM, 0, stream>>>(
      W1iu_n, W1iu_s, W2iu_n, W2iu_s, Wp1, Wp2, Wt[2], Wt[3], Wt[6], Wt[7],
      flag);
  prep_misc_kernel<<<1, CDIM, 0, stream>>>(Wpost, bpost, bp1, bp2, wsum, bpf1,
                                           bpf2, flag);

  if (useShadow) {
    // bf16 shadows of the gathered tables: halves gather traffic.
    convert_bf16_kernel<<<(NUSER * CDIM) / 2048, 256, 0, stream>>>(
        x_user, xu_sh, (long)NUSER * CDIM, flag);
    convert_bf16_kernel<<<(NITEM * CDIM) / 2048, 256, 0, stream>>>(
        x_item, xi_sh, (long)NITEM * CDIM, flag);
    // layer 1 (writes bf16 shadows of cur1 for layer-2 gathers)
    gather_gemm_kernel<false, true><<<G_ITEM, 256, 0, stream>>>(
        offI, permI, xu_sh, 0, xi_sh, 0, Wt[0], Wt[1], nullptr, past1_item,
        c1i_sh, snap, flag, d_out, OFF_C1I, NITEM / 16);
    gather_gemm_kernel<true, true><<<G_USER, 256, 0, stream>>>(
        offU, permU, xi_sh, 0, xu_sh, 0, Wt[2], Wt[3], bpf1, past1_user,
        c1u_sh, snap, flag, d_out, OFF_C1U, NUSER / 16);
    // layer 2 (gathers bf16 shadows; no shadow output needed)
    gather_gemm_kernel<false, true><<<G_ITEM, 256, 0, stream>>>(
        offI, permI, c1u_sh, 0, c1i_sh, 0, Wt[4], Wt[5], nullptr, past2_item,
        nullptr, snap, flag, d_out, OFF_C2I, NITEM / 16);
    gather_gemm_kernel<true, true><<<G_USER, 256, 0, stream>>>(
        offU, permU, c1i_sh, 0, c1u_sh, 0, Wt[6], Wt[7], bpf2, past2_user,
        nullptr, snap, flag, d_out, OFF_C2U, NUSER / 16);
  } else {
    // fallback: previously-verified dual-dtype path
    gather_gemm_kernel<false, false><<<G_ITEM, 256, 0, stream>>>(
        offI, permI, x_user, 0, x_item, 0, Wt[0], Wt[1], nullptr, past1_item,
        nullptr, snap, flag, d_out, OFF_C1I, NITEM / 16);
    gather_gemm_kernel<true, false><<<G_USER, 256, 0, stream>>>(
        offU, permU, x_item, 0, x_user, 0, Wt[2], Wt[3], bpf1, past1_user,
        nullptr, snap, flag, d_out, OFF_C1U, NUSER / 16);
    gather_gemm_kernel<false, false><<<G_ITEM, 256, 0, stream>>>(
        offI, permI, d_out, OFF_C1U, d_out, OFF_C1I, Wt[4], Wt[5], nullptr,
        past2_item, nullptr, snap, flag, d_out, OFF_C2I, NITEM / 16);
    gather_gemm_kernel<true, false><<<G_USER, 256, 0, stream>>>(
        offU, permU, d_out, OFF_C1I, d_out, OFF_C1U, Wt[6], Wt[7], bpf2,
        past2_user, nullptr, snap, flag, d_out, OFF_C2U, NUSER / 16);
  }

  // scoring (reads full-precision cur2 from d_out)
  score_kernel<<<(LBL * 16) / 256, 256, 0, stream>>>(d_out, lbl_src, lbl_dst,
                                                     wsum, flag);
}

// Round 5
// 1301.980 us; speedup vs baseline: 1.2070x; 1.2070x over previous
//
#include <hip/hip_runtime.h>

// ---------------------------------------------------------------------------
// TAOBAODurendal: 2-layer hetero GraphConv + temporal blend + link scoring.
// Round-5 design (4th submit; three prior attempts failed on infra:
// GPUAcquisitionTimeout x2, container-failed-twice x1 -- the latter also hit
// the round-0 harness-verified kernel, so these are broker-side, not kernel):
//  * NEW: block-cooperative gather tiles. rocprof showed the fused gather
//    kernels at 9.8% occupancy / 6.7% VALUBusy / 12% HBM -- latency-bound.
//    Now one 256-thread block (4 waves) owns a 16-row tile: each wave sums a
//    quarter of each row's edge list (4x shorter dependent chains, 4x more
//    concurrent gather streams), partials reduce through padded LDS, and each
//    wave then computes 2 of the 8 output col-tiles (d[2] accumulators,
//    __launch_bounds__(256,4) -> 128 VGPR cap -> 4 waves/SIMD).
//  * NEW: the two serial single-block scans merged into one 2-block dispatch.
//  * bf16 shadow tables for all gathered features (round-4): halves gather
//    bytes vs f32. Fallback to verified f32 path if ws too small.
//  * CSR build per launch (hist -> scan -> bucket), reused by both layers.
//  * _sem_agg with R=1 is identity; Wp folded into relation weights;
//    link score collapses to dot(u*i, Wpost[:,0]+Wpost[:,1]) + sum(bpost).
// ---------------------------------------------------------------------------

#define NUSER 100000
#define NITEM 50000
#define CDIM  128
#define EDGES 1000000
#define LBL   200000

// element offsets inside d_out: [h | cur1_user | cur1_item | cur2_user | cur2_item]
#define OFF_C1U ((long)LBL)
#define OFF_C1I (OFF_C1U + (long)NUSER * CDIM)
#define OFF_C2U (OFF_C1I + (long)NITEM * CDIM)
#define OFF_C2I (OFF_C2U + (long)NUSER * CDIM)

typedef __bf16 bf16x8 __attribute__((ext_vector_type(8)));
typedef float  f32x4  __attribute__((ext_vector_type(4)));

// ---- dual-dtype scalar load -------------------------------------------------
__device__ __forceinline__ float ld1(const void* base, size_t idx, bool isf32) {
  return isf32 ? ((const float*)base)[idx] : (float)((const __bf16*)base)[idx];
}

// ---- dtype probe ------------------------------------------------------------
__global__ void probe_dtype_kernel(const unsigned short* __restrict__ x,
                                   int* __restrict__ flag) {
  int t = threadIdx.x;  // 256
  int bad = 0;
  for (int i = t * 2; i < 8192; i += 512) {
    int e = (x[i] >> 7) & 0xFF;
    if (e > 0x85) bad = 1;
  }
  if (bad) atomicOr(flag, 1);
}

// ---- CSR build --------------------------------------------------------------
__global__ __launch_bounds__(256) void hist_kernel(
    const int* __restrict__ dst_ui, const int* __restrict__ dst_iu,
    int* __restrict__ cntI, int* __restrict__ cntU) {
  int e = blockIdx.x * 256 + threadIdx.x;
  if (e < EDGES) {
    atomicAdd(&cntI[dst_ui[e]], 1);
    atomicAdd(&cntU[dst_iu[e]], 1);
  }
}

// 2-block exclusive scan: block 0 scans (cntI->offI), block 1 (cntU->offU).
__global__ __launch_bounds__(1024) void scan2_kernel(
    const int* __restrict__ cntI, int* __restrict__ offI, int* __restrict__ curI,
    int nI, const int* __restrict__ cntU, int* __restrict__ offU,
    int* __restrict__ curU, int nU) {
  const int* cnt = blockIdx.x ? cntU : cntI;
  int* off = blockIdx.x ? offU : offI;
  int* cur = blockIdx.x ? curU : curI;
  int n = blockIdx.x ? nU : nI;
  __shared__ int wsums[16];
  __shared__ int carry_s;
  int t = threadIdx.x, lane = t & 63, w = t >> 6;
  if (t == 0) carry_s = 0;
  __syncthreads();
  for (int base = 0; base < n; base += 1024) {
    int i = base + t;
    int v = (i < n) ? cnt[i] : 0;
    int x = v;
#pragma unroll
    for (int s = 1; s < 64; s <<= 1) {
      int y = __shfl_up(x, s, 64);
      if (lane >= s) x += y;
    }
    if (lane == 63) wsums[w] = x;
    __syncthreads();
    int woff = 0;
    for (int ww = 0; ww < w; ++ww) woff += wsums[ww];
    int carry = carry_s;
    __syncthreads();
    int excl = carry + woff + x - v;
    if (i < n) { off[i] = excl; cur[i] = excl; }
    if (t == 1023) carry_s = excl + v;
    __syncthreads();
  }
  if (t == 0) off[n] = carry_s;
}

__global__ __launch_bounds__(256) void bucket_kernel(
    const int* __restrict__ src_ui, const int* __restrict__ dst_ui,
    const int* __restrict__ src_iu, const int* __restrict__ dst_iu,
    int* __restrict__ curI, int* __restrict__ curU,
    int* __restrict__ permI, int* __restrict__ permU) {
  int e = blockIdx.x * 256 + threadIdx.x;
  if (e < EDGES) {
    int p = atomicAdd(&curI[dst_ui[e]], 1);
    permI[p] = src_ui[e];
    int p2 = atomicAdd(&curU[dst_iu[e]], 1);
    permU[p2] = src_iu[e];
  }
}

// ---- bf16 shadow conversion -------------------------------------------------
__global__ __launch_bounds__(256) void convert_bf16_kernel(
    const void* __restrict__ in, __bf16* __restrict__ outp, long n,
    const int* __restrict__ flag) {
  bool f = flag[0] != 0;
  long i = ((long)blockIdx.x * 256 + threadIdx.x) * 8;
  if (i + 8 > n) return;
  bf16x8 o;
  if (f) {
    f32x4 a = *(const f32x4*)((const float*)in + i);
    f32x4 b = *(const f32x4*)((const float*)in + i + 4);
#pragma unroll
    for (int j = 0; j < 4; ++j) {
      o[j] = (__bf16)a[j];
      o[4 + j] = (__bf16)b[j];
    }
  } else {
    o = *(const bf16x8*)((const __bf16*)in + i);
  }
  *(bf16x8*)(outp + i) = o;
}

// ---- weight prep ------------------------------------------------------------
__global__ __launch_bounds__(128) void prep_transpose_kernel(
    const void* __restrict__ W0, const void* __restrict__ W1,
    const void* __restrict__ W2, const void* __restrict__ W3,
    __bf16* __restrict__ T0, __bf16* __restrict__ T1,
    __bf16* __restrict__ T2, __bf16* __restrict__ T3,
    const int* __restrict__ flag) {
  bool f = flag[0] != 0;
  int k = blockIdx.x, n = threadIdx.x, y = blockIdx.y;
  const void* W = (y == 0) ? W0 : (y == 1) ? W1 : (y == 2) ? W2 : W3;
  __bf16* T = (y == 0) ? T0 : (y == 1) ? T1 : (y == 2) ? T2 : T3;
  T[n * CDIM + k] = (__bf16)ld1(W, (size_t)k * CDIM + n, f);
}

// Tt = (W @ Wp)^T, f32 accumulate, bf16 store.
__global__ __launch_bounds__(128) void prep_combine_kernel(
    const void* __restrict__ W0, const void* __restrict__ W1,
    const void* __restrict__ W2, const void* __restrict__ W3,
    const void* __restrict__ Wp1, const void* __restrict__ Wp2,
    __bf16* __restrict__ T0, __bf16* __restrict__ T1,
    __bf16* __restrict__ T2, __bf16* __restrict__ T3,
    const int* __restrict__ flag) {
  bool f = flag[0] != 0;
  int k = blockIdx.x, n = threadIdx.x, y = blockIdx.y;
  const void* W = (y == 0) ? W0 : (y == 1) ? W1 : (y == 2) ? W2 : W3;
  const void* Wp = (y < 2) ? Wp1 : Wp2;
  __bf16* T = (y == 0) ? T0 : (y == 1) ? T1 : (y == 2) ? T2 : T3;
  float s = 0.f;
#pragma unroll 4
  for (int j = 0; j < CDIM; ++j)
    s += ld1(W, (size_t)k * CDIM + j, f) * ld1(Wp, (size_t)j * CDIM + n, f);
  T[n * CDIM + k] = (__bf16)s;
}

__global__ void prep_misc_kernel(const void* __restrict__ Wpost,
                                 const void* __restrict__ bpost,
                                 const void* __restrict__ bp1,
                                 const void* __restrict__ bp2,
                                 float* __restrict__ wsum,
                                 float* __restrict__ bpf1,
                                 float* __restrict__ bpf2,
                                 const int* __restrict__ flag) {
  bool f = flag[0] != 0;
  int t = threadIdx.x;  // 128
  wsum[t] = ld1(Wpost, (size_t)t * 2, f) + ld1(Wpost, (size_t)t * 2 + 1, f);
  bpf1[t] = ld1(bp1, t, f);
  bpf2[t] = ld1(bp2, t, f);
  if (t == 0) wsum[CDIM] = ld1(bpost, 0, f) + ld1(bpost, 1, f);
}

// ---- block-cooperative gather(seg-mean) + dual-GEMM + blend (shadow path) ---
// One 256-thread block per 16-row tile. Wave w sums edge-quarter w of each
// row; partials reduce via padded LDS; wave w then computes output col-tiles
// {2w, 2w+1} via MFMA. out = blend(past, mean @ WtN^T + X @ WtS^T + bias).
// mfma_f32_16x16x32_bf16 layouts (m89/m91-verified):
//   A: lane = A[m=lane&15][k=(lane>>4)*8+j+ks*32]; B from Wt[n][k] storage;
//   C/D: col=lane&15, row=(lane>>4)*4+reg.
template <bool HAS_BIAS>
__global__ __launch_bounds__(256, 4) void gather_gemm_coop(
    const int* __restrict__ off, const int* __restrict__ perm,
    const __bf16* __restrict__ feat, const __bf16* __restrict__ X,
    const __bf16* __restrict__ WtN, const __bf16* __restrict__ WtS,
    const float* __restrict__ bias, const void* __restrict__ past,
    __bf16* __restrict__ shadow_out, const int* __restrict__ snapp,
    const int* __restrict__ flag, void* __restrict__ outb, long outoff,
    int nRowTiles) {
  __shared__ float lds[4][16][132];  // +4 pad: spreads q-groups across banks
  bool f32o = (flag[0] != 0);
  bool blend = (snapp[0] != 0);
  int t = threadIdx.x;
  int w = t >> 6, lane = t & 63, ln = lane & 15, q = lane >> 4;
  int cq = q * 8;
  for (int rt = blockIdx.x; rt < nRowTiles; rt += gridDim.x) {
    int row = rt * 16 + ln;
    int beg = off[row], end = off[row + 1];
    int cnt = end - beg;
    int myBeg = beg + ((cnt * w) >> 2);
    int myEnd = beg + ((cnt * (w + 1)) >> 2);
    // ---- phase A: per-wave partial edge sums (quarter of each row) ----
    float s[4][8];
#pragma unroll
    for (int a = 0; a < 4; ++a)
#pragma unroll
      for (int j = 0; j < 8; ++j) s[a][j] = 0.f;
    {
      const __bf16* fb = feat + cq;
      int i = myBeg;
      for (; i + 1 < myEnd; i += 2) {
        const __bf16* fp0 = fb + (size_t)perm[i] * CDIM;
        const __bf16* fp1 = fb + (size_t)perm[i + 1] * CDIM;
        bf16x8 v0[4], v1[4];
#pragma unroll
        for (int ks = 0; ks < 4; ++ks) v0[ks] = *(const bf16x8*)(fp0 + ks * 32);
#pragma unroll
        for (int ks = 0; ks < 4; ++ks) v1[ks] = *(const bf16x8*)(fp1 + ks * 32);
#pragma unroll
        for (int ks = 0; ks < 4; ++ks)
#pragma unroll
          for (int j = 0; j < 8; ++j)
            s[ks][j] += (float)v0[ks][j] + (float)v1[ks][j];
      }
      if (i < myEnd) {
        const __bf16* fp = fb + (size_t)perm[i] * CDIM;
#pragma unroll
        for (int ks = 0; ks < 4; ++ks) {
          bf16x8 v = *(const bf16x8*)(fp + ks * 32);
#pragma unroll
          for (int j = 0; j < 8; ++j) s[ks][j] += (float)v[j];
        }
      }
    }
#pragma unroll
    for (int ks = 0; ks < 4; ++ks) {
      *(f32x4*)&lds[w][ln][cq + ks * 32] =
          (f32x4){s[ks][0], s[ks][1], s[ks][2], s[ks][3]};
      *(f32x4*)&lds[w][ln][cq + ks * 32 + 4] =
          (f32x4){s[ks][4], s[ks][5], s[ks][6], s[ks][7]};
    }
    __syncthreads();
    // ---- phase B: reduce partials, build fragments, MFMA 2 col-tiles ----
    float rc = 1.0f / fmaxf((float)cnt, 1.0f);
    bf16x8 a1[4], a2[4];
#pragma unroll
    for (int ks = 0; ks < 4; ++ks) {
      f32x4 lo = (f32x4){0.f, 0.f, 0.f, 0.f};
      f32x4 hi = (f32x4){0.f, 0.f, 0.f, 0.f};
#pragma unroll
      for (int w2 = 0; w2 < 4; ++w2) {
        const float* p = &lds[w2][ln][cq + ks * 32];
        lo += *(const f32x4*)p;
        hi += *(const f32x4*)(p + 4);
      }
      bf16x8 t1;
#pragma unroll
      for (int j = 0; j < 4; ++j) {
        t1[j] = (__bf16)(lo[j] * rc);
        t1[4 + j] = (__bf16)(hi[j] * rc);
      }
      a1[ks] = t1;
      a2[ks] = *(const bf16x8*)(X + (size_t)row * CDIM + cq + ks * 32);
    }
    f32x4 d0 = (f32x4){0.f, 0.f, 0.f, 0.f};
    f32x4 d1 = (f32x4){0.f, 0.f, 0.f, 0.f};
    const __bf16* bn0 = WtN + (size_t)((2 * w) * 16 + ln) * CDIM + cq;
    const __bf16* bs0 = WtS + (size_t)((2 * w) * 16 + ln) * CDIM + cq;
#pragma unroll
    for (int ks = 0; ks < 4; ++ks) {
      d0 = __builtin_amdgcn_mfma_f32_16x16x32_bf16(
          a1[ks], *(const bf16x8*)(bn0 + ks * 32), d0, 0, 0, 0);
      d0 = __builtin_amdgcn_mfma_f32_16x16x32_bf16(
          a2[ks], *(const bf16x8*)(bs0 + ks * 32), d0, 0, 0, 0);
      d1 = __builtin_amdgcn_mfma_f32_16x16x32_bf16(
          a1[ks], *(const bf16x8*)(bn0 + 16 * CDIM + ks * 32), d1, 0, 0, 0);
      d1 = __builtin_amdgcn_mfma_f32_16x16x32_bf16(
          a2[ks], *(const bf16x8*)(bs0 + 16 * CDIM + ks * 32), d1, 0, 0, 0);
    }
    // ---- epilogue: bias + temporal blend + stores for col-tiles 2w,2w+1 ----
#pragma unroll
    for (int p = 0; p < 2; ++p) {
      f32x4 dd = p ? d1 : d0;
      int col = (2 * w + p) * 16 + ln;
      float bv = HAS_BIAS ? bias[col] : 0.0f;
#pragma unroll
      for (int r = 0; r < 4; ++r) {
        long orow = (long)rt * 16 + q * 4 + r;
        float v = dd[r] + bv;
        if (blend)
          v = 0.05f * ld1(past, (size_t)orow * CDIM + col, f32o) + 0.95f * v;
        if (shadow_out) shadow_out[(size_t)orow * CDIM + col] = (__bf16)v;
        size_t oidx = (size_t)(outoff + orow * CDIM + col);
        if (f32o)
          ((float*)outb)[oidx] = v;
        else
          ((__bf16*)outb)[oidx] = (__bf16)v;
      }
    }
    __syncthreads();  // lds reused next rt iteration (exact grid: runs once)
  }
}

// ---- fallback per-wave fused kernel (verified round-3 path, f32 gathers) ----
template <bool HAS_BIAS>
__global__ __launch_bounds__(256) void gather_gemm_kernel(
    const int* __restrict__ off, const int* __restrict__ perm,
    const void* __restrict__ featb, long featoff,
    const void* __restrict__ Xb, long xoff,
    const __bf16* __restrict__ WtN, const __bf16* __restrict__ WtS,
    const float* __restrict__ bias, const void* __restrict__ past,
    const int* __restrict__ snapp, const int* __restrict__ flag,
    void* __restrict__ outb, long outoff, int nRowTiles) {
  bool f32 = (flag[0] != 0);
  bool blend = (snapp[0] != 0);
  int lane = threadIdx.x & 63;
  int ln = lane & 15, q = lane >> 4;
  int wave = blockIdx.x * 4 + (threadIdx.x >> 6);
  int nW = gridDim.x * 4;
  size_t cq = (size_t)q * 8;
  for (int rt = wave; rt < nRowTiles; rt += nW) {
    int row = rt * 16 + ln;
    int beg = off[row], end = off[row + 1];
    float s[4][8];
#pragma unroll
    for (int a = 0; a < 4; ++a)
#pragma unroll
      for (int j = 0; j < 8; ++j) s[a][j] = 0.f;
    if (f32) {
      const float* fb = (const float*)featb + featoff + cq;
      for (int i = beg; i < end; ++i) {
        const float* fp = fb + (size_t)perm[i] * CDIM;
#pragma unroll
        for (int ks = 0; ks < 4; ++ks) {
          f32x4 lo = *(const f32x4*)(fp + ks * 32);
          f32x4 hi = *(const f32x4*)(fp + ks * 32 + 4);
#pragma unroll
          for (int j = 0; j < 4; ++j) {
            s[ks][j] += lo[j];
            s[ks][4 + j] += hi[j];
          }
        }
      }
    } else {
      const __bf16* fb = (const __bf16*)featb + featoff + cq;
      for (int i = beg; i < end; ++i) {
        const __bf16* fp = fb + (size_t)perm[i] * CDIM;
#pragma unroll
        for (int ks = 0; ks < 4; ++ks) {
          bf16x8 v = *(const bf16x8*)(fp + ks * 32);
#pragma unroll
          for (int j = 0; j < 8; ++j) s[ks][j] += (float)v[j];
        }
      }
    }
    float rc = 1.0f / fmaxf((float)(end - beg), 1.0f);
    bf16x8 a1[4], a2[4];
    size_t xb = (size_t)row * CDIM + cq;
#pragma unroll
    for (int ks = 0; ks < 4; ++ks) {
      bf16x8 t1, t2;
      if (f32) {
        const float* xp = (const float*)Xb + xoff + xb + ks * 32;
        f32x4 lo = *(const f32x4*)xp;
        f32x4 hi = *(const f32x4*)(xp + 4);
#pragma unroll
        for (int j = 0; j < 4; ++j) {
          t2[j] = (__bf16)lo[j];
          t2[4 + j] = (__bf16)hi[j];
        }
      } else {
        t2 = *(const bf16x8*)((const __bf16*)Xb + xoff + xb + ks * 32);
      }
#pragma unroll
      for (int j = 0; j < 8; ++j) t1[j] = (__bf16)(s[ks][j] * rc);
      a1[ks] = t1;
      a2[ks] = t2;
    }
    f32x4 d[8];
#pragma unroll
    for (int ct = 0; ct < 8; ++ct) d[ct] = (f32x4){0.f, 0.f, 0.f, 0.f};
#pragma unroll
    for (int ct = 0; ct < 8; ++ct) {
      const __bf16* bn = WtN + (size_t)(ct * 16 + ln) * CDIM + q * 8;
      const __bf16* bs = WtS + (size_t)(ct * 16 + ln) * CDIM + q * 8;
#pragma unroll
      for (int ks = 0; ks < 4; ++ks) {
        d[ct] = __builtin_amdgcn_mfma_f32_16x16x32_bf16(
            a1[ks], *(const bf16x8*)(bn + ks * 32), d[ct], 0, 0, 0);
        d[ct] = __builtin_amdgcn_mfma_f32_16x16x32_bf16(
            a2[ks], *(const bf16x8*)(bs + ks * 32), d[ct], 0, 0, 0);
      }
    }
#pragma unroll
    for (int ct = 0; ct < 8; ++ct) {
      int col = ct * 16 + ln;
      float bv = HAS_BIAS ? bias[col] : 0.0f;
#pragma unroll
      for (int r = 0; r < 4; ++r) {
        long orow = rt * 16 + q * 4 + r;
        float v = d[ct][r] + bv;
        if (blend)
          v = 0.05f * ld1(past, (size_t)orow * CDIM + col, f32) + 0.95f * v;
        size_t oidx = (size_t)(outoff + orow * CDIM + col);
        if (f32)
          ((float*)outb)[oidx] = v;
        else
          ((__bf16*)outb)[oidx] = (__bf16)v;
      }
    }
  }
}

// ---- link scoring -----------------------------------------------------------
__global__ __launch_bounds__(256) void score_kernel(
    void* __restrict__ outb, const int* __restrict__ ls,
    const int* __restrict__ ld, const float* __restrict__ wsum,
    const int* __restrict__ flag) {
  bool f32 = (flag[0] != 0);
  int t = blockIdx.x * blockDim.x + threadIdx.x;
  int l = t >> 4;
  if (l >= LBL) return;
  size_t c8 = (size_t)(t & 15) << 3;
  float av[8], bv[8];
  if (f32) {
    const float* u = (const float*)outb + OFF_C2U + (size_t)ls[l] * CDIM + c8;
    const float* v = (const float*)outb + OFF_C2I + (size_t)ld[l] * CDIM + c8;
    f32x4 u0 = *(const f32x4*)u, u1 = *(const f32x4*)(u + 4);
    f32x4 v0 = *(const f32x4*)v, v1 = *(const f32x4*)(v + 4);
#pragma unroll
    for (int j = 0; j < 4; ++j) {
      av[j] = u0[j]; av[4 + j] = u1[j];
      bv[j] = v0[j]; bv[4 + j] = v1[j];
    }
  } else {
    bf16x8 a = *(const bf16x8*)((const __bf16*)outb + OFF_C2U +
                                (size_t)ls[l] * CDIM + c8);
    bf16x8 b = *(const bf16x8*)((const __bf16*)outb + OFF_C2I +
                                (size_t)ld[l] * CDIM + c8);
#pragma unroll
    for (int j = 0; j < 8; ++j) { av[j] = (float)a[j]; bv[j] = (float)b[j]; }
  }
  float p = 0.f;
#pragma unroll
  for (int j = 0; j < 8; ++j) p += av[j] * bv[j] * wsum[c8 + j];
  p += __shfl_xor(p, 1, 16);
  p += __shfl_xor(p, 2, 16);
  p += __shfl_xor(p, 4, 16);
  p += __shfl_xor(p, 8, 16);
  if ((t & 15) == 0) {
    float h = p + wsum[CDIM];
    if (f32)
      ((float*)outb)[l] = h;
    else
      ((__bf16*)outb)[l] = (__bf16)h;
  }
}

// ---------------------------------------------------------------------------
extern "C" void kernel_launch(void* const* d_in, const int* in_sizes, int n_in,
                              void* d_out, int out_size, void* d_ws,
                              size_t ws_size, hipStream_t stream) {
  const void* x_user = d_in[0];
  const void* x_item = d_in[1];
  const void* past1_user = d_in[2];
  const void* past1_item = d_in[3];
  const void* past2_user = d_in[4];
  const void* past2_item = d_in[5];
  const void* W1ui_n = d_in[6];
  const void* W1ui_s = d_in[7];
  const void* W1iu_n = d_in[8];
  const void* W1iu_s = d_in[9];
  const void* Wp1 = d_in[10];
  const void* bp1 = d_in[11];
  const void* W2ui_n = d_in[15];
  const void* W2ui_s = d_in[16];
  const void* W2iu_n = d_in[17];
  const void* W2iu_s = d_in[18];
  const void* Wp2 = d_in[19];
  const void* bp2 = d_in[20];
  const void* Wpost = d_in[24];
  const void* bpost = d_in[25];
  const int* src_ui = (const int*)d_in[26];
  const int* dst_ui = (const int*)d_in[27];
  const int* src_iu = (const int*)d_in[28];
  const int* dst_iu = (const int*)d_in[29];
  const int* lbl_src = (const int*)d_in[30];
  const int* lbl_dst = (const int*)d_in[31];
  const int* snap = (const int*)d_in[32];

  // ---- workspace carve, 256B-aligned sections ----
  size_t wo = 0;
  auto alloc = [&](size_t bytes) -> char* {
    char* p = (char*)d_ws + wo;
    wo += (bytes + 255) & ~(size_t)255;
    return p;
  };
  int* cntI = (int*)alloc(NITEM * 4);
  int* cntU = (int*)alloc(NUSER * 4);
  int* flag = (int*)alloc(256);
  size_t zeroBytes = wo;  // cntI + cntU + flag zeroed in one memset
  int* offI = (int*)alloc((NITEM + 1) * 4);
  int* offU = (int*)alloc((NUSER + 1) * 4);
  int* curI = (int*)alloc(NITEM * 4);
  int* curU = (int*)alloc(NUSER * 4);
  int* permI = (int*)alloc(EDGES * 4);
  int* permU = (int*)alloc(EDGES * 4);
  float* wsum = (float*)alloc(256 * 4);
  float* bpf1 = (float*)alloc(CDIM * 4);
  float* bpf2 = (float*)alloc(CDIM * 4);
  __bf16* wt0 = (__bf16*)alloc(8 * CDIM * CDIM * 2);
  __bf16* Wt[8];
  for (int i = 0; i < 8; ++i) Wt[i] = wt0 + (size_t)i * CDIM * CDIM;
  // bf16 shadow tables (gather sources). Allocated last; used only if they fit.
  __bf16* xu_sh = (__bf16*)alloc((size_t)NUSER * CDIM * 2);
  __bf16* xi_sh = (__bf16*)alloc((size_t)NITEM * CDIM * 2);
  __bf16* c1u_sh = (__bf16*)alloc((size_t)NUSER * CDIM * 2);
  __bf16* c1i_sh = (__bf16*)alloc((size_t)NITEM * CDIM * 2);
  bool useShadow = (wo <= ws_size);

  const int EB = (EDGES + 255) / 256;
  const int T_ITEM = NITEM / 16;  // 3125 tiles
  const int T_USER = NUSER / 16;  // 6250 tiles

  hipMemsetAsync(d_ws, 0, zeroBytes, stream);
  probe_dtype_kernel<<<1, 256, 0, stream>>>((const unsigned short*)x_user,
                                            flag);

  // CSR build (shared by both layers)
  hist_kernel<<<EB, 256, 0, stream>>>(dst_ui, dst_iu, cntI, cntU);
  scan2_kernel<<<2, 1024, 0, stream>>>(cntI, offI, curI, NITEM, cntU, offU,
                                       curU, NUSER);
  bucket_kernel<<<EB, 256, 0, stream>>>(src_ui, dst_ui, src_iu, dst_iu, curI,
                                        curU, permI, permU);

  // weight prep: Wt0/1 = W1ui_{n,s}^T, Wt4/5 = W2ui_{n,s}^T,
  //              Wt2/3 = (W1iu_{n,s}@Wp1)^T, Wt6/7 = (W2iu_{n,s}@Wp2)^T
  prep_transpose_kernel<<<dim3(CDIM, 4), CDIM, 0, stream>>>(
      W1ui_n, W1ui_s, W2ui_n, W2ui_s, Wt[0], Wt[1], Wt[4], Wt[5], flag);
  prep_combine_kernel<<<dim3(CDIM, 4), CDIM, 0, stream>>>(
      W1iu_n, W1iu_s, W2iu_n, W2iu_s, Wp1, Wp2, Wt[2], Wt[3], Wt[6], Wt[7],
      flag);
  prep_misc_kernel<<<1, CDIM, 0, stream>>>(Wpost, bpost, bp1, bp2, wsum, bpf1,
                                           bpf2, flag);

  if (useShadow) {
    // bf16 shadows of the gathered tables: halves gather traffic.
    convert_bf16_kernel<<<(NUSER * CDIM) / 2048, 256, 0, stream>>>(
        x_user, xu_sh, (long)NUSER * CDIM, flag);
    convert_bf16_kernel<<<(NITEM * CDIM) / 2048, 256, 0, stream>>>(
        x_item, xi_sh, (long)NITEM * CDIM, flag);
    // layer 1 (writes bf16 shadows of cur1 for layer-2 gathers)
    gather_gemm_coop<false><<<T_ITEM, 256, 0, stream>>>(
        offI, permI, xu_sh, xi_sh, Wt[0], Wt[1], nullptr, past1_item, c1i_sh,
        snap, flag, d_out, OFF_C1I, T_ITEM);
    gather_gemm_coop<true><<<T_USER, 256, 0, stream>>>(
        offU, permU, xi_sh, xu_sh, Wt[2], Wt[3], bpf1, past1_user, c1u_sh,
        snap, flag, d_out, OFF_C1U, T_USER);
    // layer 2 (gathers bf16 shadows; no shadow output needed)
    gather_gemm_coop<false><<<T_ITEM, 256, 0, stream>>>(
        offI, permI, c1u_sh, c1i_sh, Wt[4], Wt[5], nullptr, past2_item,
        nullptr, snap, flag, d_out, OFF_C2I, T_ITEM);
    gather_gemm_coop<true><<<T_USER, 256, 0, stream>>>(
        offU, permU, c1i_sh, c1u_sh, Wt[6], Wt[7], bpf2, past2_user, nullptr,
        snap, flag, d_out, OFF_C2U, T_USER);
  } else {
    // fallback: previously-verified dual-dtype per-wave path
    const int G_ITEM = (T_ITEM + 3) / 4;
    const int G_USER = (T_USER + 3) / 4;
    gather_gemm_kernel<false><<<G_ITEM, 256, 0, stream>>>(
        offI, permI, x_user, 0, x_item, 0, Wt[0], Wt[1], nullptr, past1_item,
        snap, flag, d_out, OFF_C1I, T_ITEM);
    gather_gemm_kernel<true><<<G_USER, 256, 0, stream>>>(
        offU, permU, x_item, 0, x_user, 0, Wt[2], Wt[3], bpf1, past1_user,
        snap, flag, d_out, OFF_C1U, T_USER);
    gather_gemm_kernel<false><<<G_ITEM, 256, 0, stream>>>(
        offI, permI, d_out, OFF_C1U, d_out, OFF_C1I, Wt[4], Wt[5], nullptr,
        past2_item, snap, flag, d_out, OFF_C2I, T_ITEM);
    gather_gemm_kernel<true><<<G_USER, 256, 0, stream>>>(
        offU, permU, d_out, OFF_C1I, d_out, OFF_C1U, Wt[6], Wt[7], bpf2,
        past2_user, snap, flag, d_out, OFF_C2U, T_USER);
  }

  // scoring (reads full-precision cur2 from d_out)
  score_kernel<<<(LBL * 16) / 256, 256, 0, stream>>>(d_out, lbl_src, lbl_dst,
                                                     wsum, flag);
}

// Round 6
// 1255.255 us; speedup vs baseline: 1.2520x; 1.0372x over previous
//
#include <hip/hip_runtime.h>

// ---------------------------------------------------------------------------
// TAOBAODurendal: 2-layer hetero GraphConv + temporal blend + link scoring.
// Round-7 design (on top of measured round-5, 1302us):
//  * NEW: coalesced epilogue. rocprof showed WRITE_SIZE 300MB vs ~77MB ideal
//    on user gather dispatches (4x write amplification from scattered 4-B
//    stores -> partial-line RMW in L2), and scattered past reads. Now the
//    C-tile is staged in LDS (reusing the 33KB partial-sum buffer) and the
//    block writes out/shadow/past-blend with full-line coalesced accesses
//    (8 contiguous f32 per thread).
//  * Block-cooperative gather tiles (round-5, measured 232->190us/dispatch,
//    occupancy 9.8->42%): 4 waves split each row's edge list, partials
//    reduce via padded LDS, each wave MFMAs 2 of 8 col-tiles. VGPR=64.
//  * bf16 shadow tables for gathered features (round-4): halves gather bytes.
//  * CSR build per launch (hist -> scan2 -> bucket), reused by both layers.
//  * _sem_agg with R=1 is identity; Wp folded into relation weights;
//    link score collapses to dot(u*i, Wpost[:,0]+Wpost[:,1]) + sum(bpost).
// ---------------------------------------------------------------------------

#define NUSER 100000
#define NITEM 50000
#define CDIM  128
#define EDGES 1000000
#define LBL   200000

// element offsets inside d_out: [h | cur1_user | cur1_item | cur2_user | cur2_item]
#define OFF_C1U ((long)LBL)
#define OFF_C1I (OFF_C1U + (long)NUSER * CDIM)
#define OFF_C2U (OFF_C1I + (long)NITEM * CDIM)
#define OFF_C2I (OFF_C2U + (long)NUSER * CDIM)

typedef __bf16 bf16x8 __attribute__((ext_vector_type(8)));
typedef float  f32x4  __attribute__((ext_vector_type(4)));

// ---- dual-dtype scalar load -------------------------------------------------
__device__ __forceinline__ float ld1(const void* base, size_t idx, bool isf32) {
  return isf32 ? ((const float*)base)[idx] : (float)((const __bf16*)base)[idx];
}

// ---- dtype probe ------------------------------------------------------------
__global__ void probe_dtype_kernel(const unsigned short* __restrict__ x,
                                   int* __restrict__ flag) {
  int t = threadIdx.x;  // 256
  int bad = 0;
  for (int i = t * 2; i < 8192; i += 512) {
    int e = (x[i] >> 7) & 0xFF;
    if (e > 0x85) bad = 1;
  }
  if (bad) atomicOr(flag, 1);
}

// ---- CSR build --------------------------------------------------------------
__global__ __launch_bounds__(256) void hist_kernel(
    const int* __restrict__ dst_ui, const int* __restrict__ dst_iu,
    int* __restrict__ cntI, int* __restrict__ cntU) {
  int e = blockIdx.x * 256 + threadIdx.x;
  if (e < EDGES) {
    atomicAdd(&cntI[dst_ui[e]], 1);
    atomicAdd(&cntU[dst_iu[e]], 1);
  }
}

// 2-block exclusive scan: block 0 scans (cntI->offI), block 1 (cntU->offU).
__global__ __launch_bounds__(1024) void scan2_kernel(
    const int* __restrict__ cntI, int* __restrict__ offI, int* __restrict__ curI,
    int nI, const int* __restrict__ cntU, int* __restrict__ offU,
    int* __restrict__ curU, int nU) {
  const int* cnt = blockIdx.x ? cntU : cntI;
  int* off = blockIdx.x ? offU : offI;
  int* cur = blockIdx.x ? curU : curI;
  int n = blockIdx.x ? nU : nI;
  __shared__ int wsums[16];
  __shared__ int carry_s;
  int t = threadIdx.x, lane = t & 63, w = t >> 6;
  if (t == 0) carry_s = 0;
  __syncthreads();
  for (int base = 0; base < n; base += 1024) {
    int i = base + t;
    int v = (i < n) ? cnt[i] : 0;
    int x = v;
#pragma unroll
    for (int s = 1; s < 64; s <<= 1) {
      int y = __shfl_up(x, s, 64);
      if (lane >= s) x += y;
    }
    if (lane == 63) wsums[w] = x;
    __syncthreads();
    int woff = 0;
    for (int ww = 0; ww < w; ++ww) woff += wsums[ww];
    int carry = carry_s;
    __syncthreads();
    int excl = carry + woff + x - v;
    if (i < n) { off[i] = excl; cur[i] = excl; }
    if (t == 1023) carry_s = excl + v;
    __syncthreads();
  }
  if (t == 0) off[n] = carry_s;
}

__global__ __launch_bounds__(256) void bucket_kernel(
    const int* __restrict__ src_ui, const int* __restrict__ dst_ui,
    const int* __restrict__ src_iu, const int* __restrict__ dst_iu,
    int* __restrict__ curI, int* __restrict__ curU,
    int* __restrict__ permI, int* __restrict__ permU) {
  int e = blockIdx.x * 256 + threadIdx.x;
  if (e < EDGES) {
    int p = atomicAdd(&curI[dst_ui[e]], 1);
    permI[p] = src_ui[e];
    int p2 = atomicAdd(&curU[dst_iu[e]], 1);
    permU[p2] = src_iu[e];
  }
}

// ---- bf16 shadow conversion -------------------------------------------------
__global__ __launch_bounds__(256) void convert_bf16_kernel(
    const void* __restrict__ in, __bf16* __restrict__ outp, long n,
    const int* __restrict__ flag) {
  bool f = flag[0] != 0;
  long i = ((long)blockIdx.x * 256 + threadIdx.x) * 8;
  if (i + 8 > n) return;
  bf16x8 o;
  if (f) {
    f32x4 a = *(const f32x4*)((const float*)in + i);
    f32x4 b = *(const f32x4*)((const float*)in + i + 4);
#pragma unroll
    for (int j = 0; j < 4; ++j) {
      o[j] = (__bf16)a[j];
      o[4 + j] = (__bf16)b[j];
    }
  } else {
    o = *(const bf16x8*)((const __bf16*)in + i);
  }
  *(bf16x8*)(outp + i) = o;
}

// ---- weight prep ------------------------------------------------------------
__global__ __launch_bounds__(128) void prep_transpose_kernel(
    const void* __restrict__ W0, const void* __restrict__ W1,
    const void* __restrict__ W2, const void* __restrict__ W3,
    __bf16* __restrict__ T0, __bf16* __restrict__ T1,
    __bf16* __restrict__ T2, __bf16* __restrict__ T3,
    const int* __restrict__ flag) {
  bool f = flag[0] != 0;
  int k = blockIdx.x, n = threadIdx.x, y = blockIdx.y;
  const void* W = (y == 0) ? W0 : (y == 1) ? W1 : (y == 2) ? W2 : W3;
  __bf16* T = (y == 0) ? T0 : (y == 1) ? T1 : (y == 2) ? T2 : T3;
  T[n * CDIM + k] = (__bf16)ld1(W, (size_t)k * CDIM + n, f);
}

// Tt = (W @ Wp)^T, f32 accumulate, bf16 store.
__global__ __launch_bounds__(128) void prep_combine_kernel(
    const void* __restrict__ W0, const void* __restrict__ W1,
    const void* __restrict__ W2, const void* __restrict__ W3,
    const void* __restrict__ Wp1, const void* __restrict__ Wp2,
    __bf16* __restrict__ T0, __bf16* __restrict__ T1,
    __bf16* __restrict__ T2, __bf16* __restrict__ T3,
    const int* __restrict__ flag) {
  bool f = flag[0] != 0;
  int k = blockIdx.x, n = threadIdx.x, y = blockIdx.y;
  const void* W = (y == 0) ? W0 : (y == 1) ? W1 : (y == 2) ? W2 : W3;
  const void* Wp = (y < 2) ? Wp1 : Wp2;
  __bf16* T = (y == 0) ? T0 : (y == 1) ? T1 : (y == 2) ? T2 : T3;
  float s = 0.f;
#pragma unroll 4
  for (int j = 0; j < CDIM; ++j)
    s += ld1(W, (size_t)k * CDIM + j, f) * ld1(Wp, (size_t)j * CDIM + n, f);
  T[n * CDIM + k] = (__bf16)s;
}

__global__ void prep_misc_kernel(const void* __restrict__ Wpost,
                                 const void* __restrict__ bpost,
                                 const void* __restrict__ bp1,
                                 const void* __restrict__ bp2,
                                 float* __restrict__ wsum,
                                 float* __restrict__ bpf1,
                                 float* __restrict__ bpf2,
                                 const int* __restrict__ flag) {
  bool f = flag[0] != 0;
  int t = threadIdx.x;  // 128
  wsum[t] = ld1(Wpost, (size_t)t * 2, f) + ld1(Wpost, (size_t)t * 2 + 1, f);
  bpf1[t] = ld1(bp1, t, f);
  bpf2[t] = ld1(bp2, t, f);
  if (t == 0) wsum[CDIM] = ld1(bpost, 0, f) + ld1(bpost, 1, f);
}

// ---- block-cooperative gather(seg-mean) + dual-GEMM + blend (shadow path) ---
// One 256-thread block per 16-row tile. Wave w sums edge-quarter w of each
// row; partials reduce via padded LDS; wave w then computes output col-tiles
// {2w, 2w+1} via MFMA. out = blend(past, mean @ WtN^T + X @ WtS^T + bias).
// Phase C stages the C-tile in LDS and writes out/shadow (+past blend read)
// fully coalesced: 8 contiguous f32 per thread = full 128-B lines (fixes the
// 4x WRITE_SIZE amplification measured in round 5: 300MB vs 77MB ideal).
// mfma_f32_16x16x32_bf16 layouts (m89/m91-verified):
//   A: lane = A[m=lane&15][k=(lane>>4)*8+j+ks*32]; B from Wt[n][k] storage;
//   C/D: col=lane&15, row=(lane>>4)*4+reg.
template <bool HAS_BIAS>
__global__ __launch_bounds__(256, 4) void gather_gemm_coop(
    const int* __restrict__ off, const int* __restrict__ perm,
    const __bf16* __restrict__ feat, const __bf16* __restrict__ X,
    const __bf16* __restrict__ WtN, const __bf16* __restrict__ WtS,
    const float* __restrict__ bias, const void* __restrict__ past,
    __bf16* __restrict__ shadow_out, const int* __restrict__ snapp,
    const int* __restrict__ flag, void* __restrict__ outb, long outoff,
    int nRowTiles) {
  __shared__ float lds[4][16][132];  // phase A/B partials; phase C reuses
  float* ldsOut = &lds[0][0][0];     // [16][132] f32 C-tile stage (8.4 KB)
  bool f32o = (flag[0] != 0);
  bool blend = (snapp[0] != 0);
  int t = threadIdx.x;
  int w = t >> 6, lane = t & 63, ln = lane & 15, q = lane >> 4;
  int cq = q * 8;
  for (int rt = blockIdx.x; rt < nRowTiles; rt += gridDim.x) {
    int row = rt * 16 + ln;
    int beg = off[row], end = off[row + 1];
    int cnt = end - beg;
    int myBeg = beg + ((cnt * w) >> 2);
    int myEnd = beg + ((cnt * (w + 1)) >> 2);
    // ---- phase A: per-wave partial edge sums (quarter of each row) ----
    float s[4][8];
#pragma unroll
    for (int a = 0; a < 4; ++a)
#pragma unroll
      for (int j = 0; j < 8; ++j) s[a][j] = 0.f;
    {
      const __bf16* fb = feat + cq;
      int i = myBeg;
      for (; i + 1 < myEnd; i += 2) {
        const __bf16* fp0 = fb + (size_t)perm[i] * CDIM;
        const __bf16* fp1 = fb + (size_t)perm[i + 1] * CDIM;
        bf16x8 v0[4], v1[4];
#pragma unroll
        for (int ks = 0; ks < 4; ++ks) v0[ks] = *(const bf16x8*)(fp0 + ks * 32);
#pragma unroll
        for (int ks = 0; ks < 4; ++ks) v1[ks] = *(const bf16x8*)(fp1 + ks * 32);
#pragma unroll
        for (int ks = 0; ks < 4; ++ks)
#pragma unroll
          for (int j = 0; j < 8; ++j)
            s[ks][j] += (float)v0[ks][j] + (float)v1[ks][j];
      }
      if (i < myEnd) {
        const __bf16* fp = fb + (size_t)perm[i] * CDIM;
#pragma unroll
        for (int ks = 0; ks < 4; ++ks) {
          bf16x8 v = *(const bf16x8*)(fp + ks * 32);
#pragma unroll
          for (int j = 0; j < 8; ++j) s[ks][j] += (float)v[j];
        }
      }
    }
#pragma unroll
    for (int ks = 0; ks < 4; ++ks) {
      *(f32x4*)&lds[w][ln][cq + ks * 32] =
          (f32x4){s[ks][0], s[ks][1], s[ks][2], s[ks][3]};
      *(f32x4*)&lds[w][ln][cq + ks * 32 + 4] =
          (f32x4){s[ks][4], s[ks][5], s[ks][6], s[ks][7]};
    }
    __syncthreads();
    // ---- phase B: reduce partials, build fragments, MFMA 2 col-tiles ----
    float rc = 1.0f / fmaxf((float)cnt, 1.0f);
    bf16x8 a1[4], a2[4];
#pragma unroll
    for (int ks = 0; ks < 4; ++ks) {
      f32x4 lo = (f32x4){0.f, 0.f, 0.f, 0.f};
      f32x4 hi = (f32x4){0.f, 0.f, 0.f, 0.f};
#pragma unroll
      for (int w2 = 0; w2 < 4; ++w2) {
        const float* p = &lds[w2][ln][cq + ks * 32];
        lo += *(const f32x4*)p;
        hi += *(const f32x4*)(p + 4);
      }
      bf16x8 t1;
#pragma unroll
      for (int j = 0; j < 4; ++j) {
        t1[j] = (__bf16)(lo[j] * rc);
        t1[4 + j] = (__bf16)(hi[j] * rc);
      }
      a1[ks] = t1;
      a2[ks] = *(const bf16x8*)(X + (size_t)row * CDIM + cq + ks * 32);
    }
    f32x4 d0 = (f32x4){0.f, 0.f, 0.f, 0.f};
    f32x4 d1 = (f32x4){0.f, 0.f, 0.f, 0.f};
    const __bf16* bn0 = WtN + (size_t)((2 * w) * 16 + ln) * CDIM + cq;
    const __bf16* bs0 = WtS + (size_t)((2 * w) * 16 + ln) * CDIM + cq;
#pragma unroll
    for (int ks = 0; ks < 4; ++ks) {
      d0 = __builtin_amdgcn_mfma_f32_16x16x32_bf16(
          a1[ks], *(const bf16x8*)(bn0 + ks * 32), d0, 0, 0, 0);
      d0 = __builtin_amdgcn_mfma_f32_16x16x32_bf16(
          a2[ks], *(const bf16x8*)(bs0 + ks * 32), d0, 0, 0, 0);
      d1 = __builtin_amdgcn_mfma_f32_16x16x32_bf16(
          a1[ks], *(const bf16x8*)(bn0 + 16 * CDIM + ks * 32), d1, 0, 0, 0);
      d1 = __builtin_amdgcn_mfma_f32_16x16x32_bf16(
          a2[ks], *(const bf16x8*)(bs0 + 16 * CDIM + ks * 32), d1, 0, 0, 0);
    }
    // ---- phase C: stage C-tile (+bias) in LDS, then coalesced epilogue ----
    __syncthreads();  // all phase-B LDS reads done before ldsOut overwrite
#pragma unroll
    for (int p = 0; p < 2; ++p) {
      f32x4 dd = p ? d1 : d0;
      int col = (2 * w + p) * 16 + ln;
      float bv = HAS_BIAS ? bias[col] : 0.0f;
#pragma unroll
      for (int r = 0; r < 4; ++r)
        ldsOut[(q * 4 + r) * 132 + col] = dd[r] + bv;  // 2-way bank: free
    }
    __syncthreads();
    {
      // 256 threads cover 16x128: thread t -> row t>>4, cols (t&15)*8..+7
      int orow16 = t >> 4, c0 = (t & 15) * 8;
      long orow = (long)rt * 16 + orow16;
      const float* lp = ldsOut + orow16 * 132 + c0;
      f32x4 v0 = *(const f32x4*)lp;
      f32x4 v1 = *(const f32x4*)(lp + 4);
      if (blend) {
        if (f32o) {
          const float* pp = (const float*)past + orow * CDIM + c0;
          f32x4 p0 = *(const f32x4*)pp;
          f32x4 p1 = *(const f32x4*)(pp + 4);
#pragma unroll
          for (int j = 0; j < 4; ++j) {
            v0[j] = 0.05f * p0[j] + 0.95f * v0[j];
            v1[j] = 0.05f * p1[j] + 0.95f * v1[j];
          }
        } else {
          bf16x8 pb =
              *(const bf16x8*)((const __bf16*)past + orow * CDIM + c0);
#pragma unroll
          for (int j = 0; j < 4; ++j) {
            v0[j] = 0.05f * (float)pb[j] + 0.95f * v0[j];
            v1[j] = 0.05f * (float)pb[4 + j] + 0.95f * v1[j];
          }
        }
      }
      if (shadow_out) {
        bf16x8 sh;
#pragma unroll
        for (int j = 0; j < 4; ++j) {
          sh[j] = (__bf16)v0[j];
          sh[4 + j] = (__bf16)v1[j];
        }
        *(bf16x8*)(shadow_out + orow * CDIM + c0) = sh;
      }
      if (f32o) {
        float* op = (float*)outb + outoff + orow * CDIM + c0;
        *(f32x4*)op = v0;
        *(f32x4*)(op + 4) = v1;
      } else {
        bf16x8 ob;
#pragma unroll
        for (int j = 0; j < 4; ++j) {
          ob[j] = (__bf16)v0[j];
          ob[4 + j] = (__bf16)v1[j];
        }
        *(bf16x8*)((__bf16*)outb + outoff + orow * CDIM + c0) = ob;
      }
    }
    __syncthreads();  // lds reused next rt iteration (exact grid: runs once)
  }
}

// ---- fallback per-wave fused kernel (verified round-3 path, f32 gathers) ----
template <bool HAS_BIAS>
__global__ __launch_bounds__(256) void gather_gemm_kernel(
    const int* __restrict__ off, const int* __restrict__ perm,
    const void* __restrict__ featb, long featoff,
    const void* __restrict__ Xb, long xoff,
    const __bf16* __restrict__ WtN, const __bf16* __restrict__ WtS,
    const float* __restrict__ bias, const void* __restrict__ past,
    const int* __restrict__ snapp, const int* __restrict__ flag,
    void* __restrict__ outb, long outoff, int nRowTiles) {
  bool f32 = (flag[0] != 0);
  bool blend = (snapp[0] != 0);
  int lane = threadIdx.x & 63;
  int ln = lane & 15, q = lane >> 4;
  int wave = blockIdx.x * 4 + (threadIdx.x >> 6);
  int nW = gridDim.x * 4;
  size_t cq = (size_t)q * 8;
  for (int rt = wave; rt < nRowTiles; rt += nW) {
    int row = rt * 16 + ln;
    int beg = off[row], end = off[row + 1];
    float s[4][8];
#pragma unroll
    for (int a = 0; a < 4; ++a)
#pragma unroll
      for (int j = 0; j < 8; ++j) s[a][j] = 0.f;
    if (f32) {
      const float* fb = (const float*)featb + featoff + cq;
      for (int i = beg; i < end; ++i) {
        const float* fp = fb + (size_t)perm[i] * CDIM;
#pragma unroll
        for (int ks = 0; ks < 4; ++ks) {
          f32x4 lo = *(const f32x4*)(fp + ks * 32);
          f32x4 hi = *(const f32x4*)(fp + ks * 32 + 4);
#pragma unroll
          for (int j = 0; j < 4; ++j) {
            s[ks][j] += lo[j];
            s[ks][4 + j] += hi[j];
          }
        }
      }
    } else {
      const __bf16* fb = (const __bf16*)featb + featoff + cq;
      for (int i = beg; i < end; ++i) {
        const __bf16* fp = fb + (size_t)perm[i] * CDIM;
#pragma unroll
        for (int ks = 0; ks < 4; ++ks) {
          bf16x8 v = *(const bf16x8*)(fp + ks * 32);
#pragma unroll
          for (int j = 0; j < 8; ++j) s[ks][j] += (float)v[j];
        }
      }
    }
    float rc = 1.0f / fmaxf((float)(end - beg), 1.0f);
    bf16x8 a1[4], a2[4];
    size_t xb = (size_t)row * CDIM + cq;
#pragma unroll
    for (int ks = 0; ks < 4; ++ks) {
      bf16x8 t1, t2;
      if (f32) {
        const float* xp = (const float*)Xb + xoff + xb + ks * 32;
        f32x4 lo = *(const f32x4*)xp;
        f32x4 hi = *(const f32x4*)(xp + 4);
#pragma unroll
        for (int j = 0; j < 4; ++j) {
          t2[j] = (__bf16)lo[j];
          t2[4 + j] = (__bf16)hi[j];
        }
      } else {
        t2 = *(const bf16x8*)((const __bf16*)Xb + xoff + xb + ks * 32);
      }
#pragma unroll
      for (int j = 0; j < 8; ++j) t1[j] = (__bf16)(s[ks][j] * rc);
      a1[ks] = t1;
      a2[ks] = t2;
    }
    f32x4 d[8];
#pragma unroll
    for (int ct = 0; ct < 8; ++ct) d[ct] = (f32x4){0.f, 0.f, 0.f, 0.f};
#pragma unroll
    for (int ct = 0; ct < 8; ++ct) {
      const __bf16* bn = WtN + (size_t)(ct * 16 + ln) * CDIM + q * 8;
      const __bf16* bs = WtS + (size_t)(ct * 16 + ln) * CDIM + q * 8;
#pragma unroll
      for (int ks = 0; ks < 4; ++ks) {
        d[ct] = __builtin_amdgcn_mfma_f32_16x16x32_bf16(
            a1[ks], *(const bf16x8*)(bn + ks * 32), d[ct], 0, 0, 0);
        d[ct] = __builtin_amdgcn_mfma_f32_16x16x32_bf16(
            a2[ks], *(const bf16x8*)(bs + ks * 32), d[ct], 0, 0, 0);
      }
    }
#pragma unroll
    for (int ct = 0; ct < 8; ++ct) {
      int col = ct * 16 + ln;
      float bv = HAS_BIAS ? bias[col] : 0.0f;
#pragma unroll
      for (int r = 0; r < 4; ++r) {
        long orow = rt * 16 + q * 4 + r;
        float v = d[ct][r] + bv;
        if (blend)
          v = 0.05f * ld1(past, (size_t)orow * CDIM + col, f32) + 0.95f * v;
        size_t oidx = (size_t)(outoff + orow * CDIM + col);
        if (f32)
          ((float*)outb)[oidx] = v;
        else
          ((__bf16*)outb)[oidx] = (__bf16)v;
      }
    }
  }
}

// ---- link scoring -----------------------------------------------------------
__global__ __launch_bounds__(256) void score_kernel(
    void* __restrict__ outb, const int* __restrict__ ls,
    const int* __restrict__ ld, const float* __restrict__ wsum,
    const int* __restrict__ flag) {
  bool f32 = (flag[0] != 0);
  int t = blockIdx.x * blockDim.x + threadIdx.x;
  int l = t >> 4;
  if (l >= LBL) return;
  size_t c8 = (size_t)(t & 15) << 3;
  float av[8], bv[8];
  if (f32) {
    const float* u = (const float*)outb + OFF_C2U + (size_t)ls[l] * CDIM + c8;
    const float* v = (const float*)outb + OFF_C2I + (size_t)ld[l] * CDIM + c8;
    f32x4 u0 = *(const f32x4*)u, u1 = *(const f32x4*)(u + 4);
    f32x4 v0 = *(const f32x4*)v, v1 = *(const f32x4*)(v + 4);
#pragma unroll
    for (int j = 0; j < 4; ++j) {
      av[j] = u0[j]; av[4 + j] = u1[j];
      bv[j] = v0[j]; bv[4 + j] = v1[j];
    }
  } else {
    bf16x8 a = *(const bf16x8*)((const __bf16*)outb + OFF_C2U +
                                (size_t)ls[l] * CDIM + c8);
    bf16x8 b = *(const bf16x8*)((const __bf16*)outb + OFF_C2I +
                                (size_t)ld[l] * CDIM + c8);
#pragma unroll
    for (int j = 0; j < 8; ++j) { av[j] = (float)a[j]; bv[j] = (float)b[j]; }
  }
  float p = 0.f;
#pragma unroll
  for (int j = 0; j < 8; ++j) p += av[j] * bv[j] * wsum[c8 + j];
  p += __shfl_xor(p, 1, 16);
  p += __shfl_xor(p, 2, 16);
  p += __shfl_xor(p, 4, 16);
  p += __shfl_xor(p, 8, 16);
  if ((t & 15) == 0) {
    float h = p + wsum[CDIM];
    if (f32)
      ((float*)outb)[l] = h;
    else
      ((__bf16*)outb)[l] = (__bf16)h;
  }
}

// ---------------------------------------------------------------------------
extern "C" void kernel_launch(void* const* d_in, const int* in_sizes, int n_in,
                              void* d_out, int out_size, void* d_ws,
                              size_t ws_size, hipStream_t stream) {
  const void* x_user = d_in[0];
  const void* x_item = d_in[1];
  const void* past1_user = d_in[2];
  const void* past1_item = d_in[3];
  const void* past2_user = d_in[4];
  const void* past2_item = d_in[5];
  const void* W1ui_n = d_in[6];
  const void* W1ui_s = d_in[7];
  const void* W1iu_n = d_in[8];
  const void* W1iu_s = d_in[9];
  const void* Wp1 = d_in[10];
  const void* bp1 = d_in[11];
  const void* W2ui_n = d_in[15];
  const void* W2ui_s = d_in[16];
  const void* W2iu_n = d_in[17];
  const void* W2iu_s = d_in[18];
  const void* Wp2 = d_in[19];
  const void* bp2 = d_in[20];
  const void* Wpost = d_in[24];
  const void* bpost = d_in[25];
  const int* src_ui = (const int*)d_in[26];
  const int* dst_ui = (const int*)d_in[27];
  const int* src_iu = (const int*)d_in[28];
  const int* dst_iu = (const int*)d_in[29];
  const int* lbl_src = (const int*)d_in[30];
  const int* lbl_dst = (const int*)d_in[31];
  const int* snap = (const int*)d_in[32];

  // ---- workspace carve, 256B-aligned sections ----
  size_t wo = 0;
  auto alloc = [&](size_t bytes) -> char* {
    char* p = (char*)d_ws + wo;
    wo += (bytes + 255) & ~(size_t)255;
    return p;
  };
  int* cntI = (int*)alloc(NITEM * 4);
  int* cntU = (int*)alloc(NUSER * 4);
  int* flag = (int*)alloc(256);
  size_t zeroBytes = wo;  // cntI + cntU + flag zeroed in one memset
  int* offI = (int*)alloc((NITEM + 1) * 4);
  int* offU = (int*)alloc((NUSER + 1) * 4);
  int* curI = (int*)alloc(NITEM * 4);
  int* curU = (int*)alloc(NUSER * 4);
  int* permI = (int*)alloc(EDGES * 4);
  int* permU = (int*)alloc(EDGES * 4);
  float* wsum = (float*)alloc(256 * 4);
  float* bpf1 = (float*)alloc(CDIM * 4);
  float* bpf2 = (float*)alloc(CDIM * 4);
  __bf16* wt0 = (__bf16*)alloc(8 * CDIM * CDIM * 2);
  __bf16* Wt[8];
  for (int i = 0; i < 8; ++i) Wt[i] = wt0 + (size_t)i * CDIM * CDIM;
  // bf16 shadow tables (gather sources). Allocated last; used only if they fit.
  __bf16* xu_sh = (__bf16*)alloc((size_t)NUSER * CDIM * 2);
  __bf16* xi_sh = (__bf16*)alloc((size_t)NITEM * CDIM * 2);
  __bf16* c1u_sh = (__bf16*)alloc((size_t)NUSER * CDIM * 2);
  __bf16* c1i_sh = (__bf16*)alloc((size_t)NITEM * CDIM * 2);
  bool useShadow = (wo <= ws_size);

  const int EB = (EDGES + 255) / 256;
  const int T_ITEM = NITEM / 16;  // 3125 tiles
  const int T_USER = NUSER / 16;  // 6250 tiles

  hipMemsetAsync(d_ws, 0, zeroBytes, stream);
  probe_dtype_kernel<<<1, 256, 0, stream>>>((const unsigned short*)x_user,
                                            flag);

  // CSR build (shared by both layers)
  hist_kernel<<<EB, 256, 0, stream>>>(dst_ui, dst_iu, cntI, cntU);
  scan2_kernel<<<2, 1024, 0, stream>>>(cntI, offI, curI, NITEM, cntU, offU,
                                       curU, NUSER);
  bucket_kernel<<<EB, 256, 0, stream>>>(src_ui, dst_ui, src_iu, dst_iu, curI,
                                        curU, permI, permU);

  // weight prep: Wt0/1 = W1ui_{n,s}^T, Wt4/5 = W2ui_{n,s}^T,
  //              Wt2/3 = (W1iu_{n,s}@Wp1)^T, Wt6/7 = (W2iu_{n,s}@Wp2)^T
  prep_transpose_kernel<<<dim3(CDIM, 4), CDIM, 0, stream>>>(
      W1ui_n, W1ui_s, W2ui_n, W2ui_s, Wt[0], Wt[1], Wt[4], Wt[5], flag);
  prep_combine_kernel<<<dim3(CDIM, 4), CDIM, 0, stream>>>(
      W1iu_n, W1iu_s, W2iu_n, W2iu_s, Wp1, Wp2, Wt[2], Wt[3], Wt[6], Wt[7],
      flag);
  prep_misc_kernel<<<1, CDIM, 0, stream>>>(Wpost, bpost, bp1, bp2, wsum, bpf1,
                                           bpf2, flag);

  if (useShadow) {
    // bf16 shadows of the gathered tables: halves gather traffic.
    convert_bf16_kernel<<<(NUSER * CDIM) / 2048, 256, 0, stream>>>(
        x_user, xu_sh, (long)NUSER * CDIM, flag);
    convert_bf16_kernel<<<(NITEM * CDIM) / 2048, 256, 0, stream>>>(
        x_item, xi_sh, (long)NITEM * CDIM, flag);
    // layer 1 (writes bf16 shadows of cur1 for layer-2 gathers)
    gather_gemm_coop<false><<<T_ITEM, 256, 0, stream>>>(
        offI, permI, xu_sh, xi_sh, Wt[0], Wt[1], nullptr, past1_item, c1i_sh,
        snap, flag, d_out, OFF_C1I, T_ITEM);
    gather_gemm_coop<true><<<T_USER, 256, 0, stream>>>(
        offU, permU, xi_sh, xu_sh, Wt[2], Wt[3], bpf1, past1_user, c1u_sh,
        snap, flag, d_out, OFF_C1U, T_USER);
    // layer 2 (gathers bf16 shadows; no shadow output needed)
    gather_gemm_coop<false><<<T_ITEM, 256, 0, stream>>>(
        offI, permI, c1u_sh, c1i_sh, Wt[4], Wt[5], nullptr, past2_item,
        nullptr, snap, flag, d_out, OFF_C2I, T_ITEM);
    gather_gemm_coop<true><<<T_USER, 256, 0, stream>>>(
        offU, permU, c1i_sh, c1u_sh, Wt[6], Wt[7], bpf2, past2_user, nullptr,
        snap, flag, d_out, OFF_C2U, T_USER);
  } else {
    // fallback: previously-verified dual-dtype per-wave path
    const int G_ITEM = (T_ITEM + 3) / 4;
    const int G_USER = (T_USER + 3) / 4;
    gather_gemm_kernel<false><<<G_ITEM, 256, 0, stream>>>(
        offI, permI, x_user, 0, x_item, 0, Wt[0], Wt[1], nullptr, past1_item,
        snap, flag, d_out, OFF_C1I, T_ITEM);
    gather_gemm_kernel<true><<<G_USER, 256, 0, stream>>>(
        offU, permU, x_item, 0, x_user, 0, Wt[2], Wt[3], bpf1, past1_user,
        snap, flag, d_out, OFF_C1U, T_USER);
    gather_gemm_kernel<false><<<G_ITEM, 256, 0, stream>>>(
        offI, permI, d_out, OFF_C1U, d_out, OFF_C1I, Wt[4], Wt[5], nullptr,
        past2_item, snap, flag, d_out, OFF_C2I, T_ITEM);
    gather_gemm_kernel<true><<<G_USER, 256, 0, stream>>>(
        offU, permU, d_out, OFF_C1I, d_out, OFF_C1U, Wt[6], Wt[7], bpf2,
        past2_user, snap, flag, d_out, OFF_C2U, T_USER);
  }

  // scoring (reads full-precision cur2 from d_out)
  score_kernel<<<(LBL * 16) / 256, 256, 0, stream>>>(d_out, lbl_src, lbl_dst,
                                                     wsum, flag);
}

// Round 8
// 1145.158 us; speedup vs baseline: 1.3723x; 1.0961x over previous
//
#include <hip/hip_runtime.h>

// ---------------------------------------------------------------------------
// TAOBAODurendal: 2-layer hetero GraphConv + temporal blend + link scoring.
// Round-8 design (2nd submit; 1st hit GPUAcquisitionTimeout, broker-side):
//  * NEW: CSR build via two-pass block-stable partition. rocprof showed
//    bucket_kernel as the top dispatch (185us, WRITE_SIZE 130MB vs 8MB ideal:
//    scattered 4-B perm writes -> one 64-B partial-line writeback each).
//    Now: partA counts per-(coarse-bin, block) in LDS (+ the per-row hist),
//    scan4 scans rows and bins, partC writes packed (src,dlo) pairs into
//    per-(block,bin) contiguous segments (full lines), bucketB scatters
//    perm within one bin's L2-hot window using LDS row cursors.
//    Old hist/scan/bucket kept as fallback if workspace is too small.
//  * Coalesced LDS-staged epilogue (round-7, WRITE 300->~80MB on gathers).
//  * Block-cooperative gather tiles (round-5): 4 waves split each row's edge
//    list, padded-LDS reduce, 2 col-tiles MFMA per wave. VGPR=64, occ 42%.
//  * bf16 shadow tables for gathered features (round-4): halves gather bytes.
//  * _sem_agg with R=1 is identity; Wp folded into relation weights;
//    link score collapses to dot(u*i, Wpost[:,0]+Wpost[:,1]) + sum(bpost).
// ---------------------------------------------------------------------------

#define NUSER 100000
#define NITEM 50000
#define CDIM  128
#define EDGES 1000000
#define LBL   200000

#define NBLK  256            // partition blocks per relation
#define BINSH 10             // coarse bin = dst >> 10
#define BINW  1024
#define NBI   ((NITEM + BINW - 1) / BINW)   // 49
#define NBU   ((NUSER + BINW - 1) / BINW)   // 98

// element offsets inside d_out: [h | cur1_user | cur1_item | cur2_user | cur2_item]
#define OFF_C1U ((long)LBL)
#define OFF_C1I (OFF_C1U + (long)NUSER * CDIM)
#define OFF_C2U (OFF_C1I + (long)NITEM * CDIM)
#define OFF_C2I (OFF_C2U + (long)NUSER * CDIM)

typedef __bf16 bf16x8 __attribute__((ext_vector_type(8)));
typedef float  f32x4  __attribute__((ext_vector_type(4)));

// ---- dual-dtype scalar load -------------------------------------------------
__device__ __forceinline__ float ld1(const void* base, size_t idx, bool isf32) {
  return isf32 ? ((const float*)base)[idx] : (float)((const __bf16*)base)[idx];
}

// ---- dtype probe ------------------------------------------------------------
__global__ void probe_dtype_kernel(const unsigned short* __restrict__ x,
                                   int* __restrict__ flag) {
  int t = threadIdx.x;  // 256
  int bad = 0;
  for (int i = t * 2; i < 8192; i += 512) {
    int e = (x[i] >> 7) & 0xFF;
    if (e > 0x85) bad = 1;
  }
  if (bad) atomicOr(flag, 1);
}

// ---- CSR build, partition path ---------------------------------------------
// partA: per-row hist (global atomics) + per-(bin,block) counts -> H bin-major.
__global__ __launch_bounds__(256) void partA_kernel(
    const int* __restrict__ dst_ui, const int* __restrict__ dst_iu,
    int* __restrict__ cntI, int* __restrict__ cntU, int* __restrict__ HI,
    int* __restrict__ HU) {
  __shared__ int h[128];
  int t = threadIdx.x, b = blockIdx.x, rel = blockIdx.y;
  const int* dst = rel ? dst_iu : dst_ui;
  int* cnt = rel ? cntU : cntI;
  int* H = rel ? HU : HI;
  int nbins = rel ? NBU : NBI;
  if (t < 128) h[t] = 0;
  __syncthreads();
  const int chunk = (EDGES + NBLK - 1) / NBLK;
  int beg = b * chunk;
  int end = min(beg + chunk, EDGES);
  for (int e = beg + t; e < end; e += 256) {
    int d = dst[e];
    atomicAdd(&cnt[d], 1);
    atomicAdd(&h[d >> BINSH], 1);
  }
  __syncthreads();
  if (t < nbins) H[t * NBLK + b] = h[t];
}

// generalized exclusive scan: up to 4 independent scans, one per block.
// cur output optional (nullptr).
__global__ __launch_bounds__(1024) void scan4_kernel(
    const int* __restrict__ c0, int* __restrict__ o0, int* __restrict__ u0,
    int n0, const int* __restrict__ c1, int* __restrict__ o1,
    int* __restrict__ u1, int n1, const int* __restrict__ c2,
    int* __restrict__ o2, int n2, const int* __restrict__ c3,
    int* __restrict__ o3, int n3) {
  const int* cnt;
  int* off;
  int* cur;
  int n;
  switch (blockIdx.x) {
    case 0: cnt = c0; off = o0; cur = u0; n = n0; break;
    case 1: cnt = c1; off = o1; cur = u1; n = n1; break;
    case 2: cnt = c2; off = o2; cur = nullptr; n = n2; break;
    default: cnt = c3; off = o3; cur = nullptr; n = n3; break;
  }
  __shared__ int wsums[16];
  __shared__ int carry_s;
  int t = threadIdx.x, lane = t & 63, w = t >> 6;
  if (t == 0) carry_s = 0;
  __syncthreads();
  for (int base = 0; base < n; base += 1024) {
    int i = base + t;
    int v = (i < n) ? cnt[i] : 0;
    int x = v;
#pragma unroll
    for (int s = 1; s < 64; s <<= 1) {
      int y = __shfl_up(x, s, 64);
      if (lane >= s) x += y;
    }
    if (lane == 63) wsums[w] = x;
    __syncthreads();
    int woff = 0;
    for (int ww = 0; ww < w; ++ww) woff += wsums[ww];
    int carry = carry_s;
    __syncthreads();
    int excl = carry + woff + x - v;
    if (i < n) {
      off[i] = excl;
      if (cur) cur[i] = excl;
    }
    if (t == 1023) carry_s = excl + v;
    __syncthreads();
  }
  if (t == 0) off[n] = carry_s;
}

// partC: re-read edges (same block<->chunk map as partA), LDS cursors from
// Hoff, write packed src|(dlo<<17) into per-(block,bin) contiguous segments.
__global__ __launch_bounds__(256) void partC_kernel(
    const int* __restrict__ src_ui, const int* __restrict__ dst_ui,
    const int* __restrict__ src_iu, const int* __restrict__ dst_iu,
    const int* __restrict__ HIoff, const int* __restrict__ HUoff,
    int* __restrict__ pairsI, int* __restrict__ pairsU) {
  __shared__ int cur[128];
  int t = threadIdx.x, b = blockIdx.x, rel = blockIdx.y;
  const int* src = rel ? src_iu : src_ui;
  const int* dst = rel ? dst_iu : dst_ui;
  const int* Hoff = rel ? HUoff : HIoff;
  int* pairs = rel ? pairsU : pairsI;
  int nbins = rel ? NBU : NBI;
  if (t < 128) cur[t] = (t < nbins) ? Hoff[t * NBLK + b] : 0;
  __syncthreads();
  const int chunk = (EDGES + NBLK - 1) / NBLK;
  int beg = b * chunk;
  int end = min(beg + chunk, EDGES);
  for (int e = beg + t; e < end; e += 256) {
    int d = dst[e];
    int p = atomicAdd(&cur[d >> BINSH], 1);
    pairs[p] = src[e] | ((d & (BINW - 1)) << 17);
  }
}

// bucketB: one block per bin; LDS row cursors; scatter perm within the
// bin's L2-hot window (full-line writebacks).
__global__ __launch_bounds__(256) void bucketB_kernel(
    const int* __restrict__ HIoff, const int* __restrict__ HUoff,
    const int* __restrict__ pairsI, const int* __restrict__ pairsU,
    const int* __restrict__ offI, const int* __restrict__ offU,
    int* __restrict__ permI, int* __restrict__ permU) {
  __shared__ int rcur[BINW];
  int t = threadIdx.x, bin = blockIdx.x, rel = blockIdx.y;
  int nbins = rel ? NBU : NBI;
  if (bin >= nbins) return;
  const int* Hoff = rel ? HUoff : HIoff;
  const int* pairs = rel ? pairsU : pairsI;
  const int* off = rel ? offU : offI;
  int* perm = rel ? permU : permI;
  int nrows = rel ? NUSER : NITEM;
  int base = bin << BINSH;
  int rows = min(BINW, nrows - base);
  for (int i = t; i < rows; i += 256) rcur[i] = off[base + i];
  __syncthreads();
  int s = Hoff[bin * NBLK];
  int e = Hoff[(bin + 1) * NBLK];  // bin+1==nbins -> off[n]=EDGES, valid
  for (int i = s + t; i < e; i += 256) {
    int v = pairs[i];
    int p = atomicAdd(&rcur[v >> 17], 1);
    perm[p] = v & 0x1FFFF;
  }
}

// ---- CSR build, fallback path (verified) ------------------------------------
__global__ __launch_bounds__(256) void hist_kernel(
    const int* __restrict__ dst_ui, const int* __restrict__ dst_iu,
    int* __restrict__ cntI, int* __restrict__ cntU) {
  int e = blockIdx.x * 256 + threadIdx.x;
  if (e < EDGES) {
    atomicAdd(&cntI[dst_ui[e]], 1);
    atomicAdd(&cntU[dst_iu[e]], 1);
  }
}

__global__ __launch_bounds__(256) void bucket_kernel(
    const int* __restrict__ src_ui, const int* __restrict__ dst_ui,
    const int* __restrict__ src_iu, const int* __restrict__ dst_iu,
    int* __restrict__ curI, int* __restrict__ curU,
    int* __restrict__ permI, int* __restrict__ permU) {
  int e = blockIdx.x * 256 + threadIdx.x;
  if (e < EDGES) {
    int p = atomicAdd(&curI[dst_ui[e]], 1);
    permI[p] = src_ui[e];
    int p2 = atomicAdd(&curU[dst_iu[e]], 1);
    permU[p2] = src_iu[e];
  }
}

// ---- bf16 shadow conversion -------------------------------------------------
__global__ __launch_bounds__(256) void convert_bf16_kernel(
    const void* __restrict__ in, __bf16* __restrict__ outp, long n,
    const int* __restrict__ flag) {
  bool f = flag[0] != 0;
  long i = ((long)blockIdx.x * 256 + threadIdx.x) * 8;
  if (i + 8 > n) return;
  bf16x8 o;
  if (f) {
    f32x4 a = *(const f32x4*)((const float*)in + i);
    f32x4 b = *(const f32x4*)((const float*)in + i + 4);
#pragma unroll
    for (int j = 0; j < 4; ++j) {
      o[j] = (__bf16)a[j];
      o[4 + j] = (__bf16)b[j];
    }
  } else {
    o = *(const bf16x8*)((const __bf16*)in + i);
  }
  *(bf16x8*)(outp + i) = o;
}

// ---- weight prep ------------------------------------------------------------
__global__ __launch_bounds__(128) void prep_transpose_kernel(
    const void* __restrict__ W0, const void* __restrict__ W1,
    const void* __restrict__ W2, const void* __restrict__ W3,
    __bf16* __restrict__ T0, __bf16* __restrict__ T1,
    __bf16* __restrict__ T2, __bf16* __restrict__ T3,
    const int* __restrict__ flag) {
  bool f = flag[0] != 0;
  int k = blockIdx.x, n = threadIdx.x, y = blockIdx.y;
  const void* W = (y == 0) ? W0 : (y == 1) ? W1 : (y == 2) ? W2 : W3;
  __bf16* T = (y == 0) ? T0 : (y == 1) ? T1 : (y == 2) ? T2 : T3;
  T[n * CDIM + k] = (__bf16)ld1(W, (size_t)k * CDIM + n, f);
}

// Tt = (W @ Wp)^T, f32 accumulate, bf16 store.
__global__ __launch_bounds__(128) void prep_combine_kernel(
    const void* __restrict__ W0, const void* __restrict__ W1,
    const void* __restrict__ W2, const void* __restrict__ W3,
    const void* __restrict__ Wp1, const void* __restrict__ Wp2,
    __bf16* __restrict__ T0, __bf16* __restrict__ T1,
    __bf16* __restrict__ T2, __bf16* __restrict__ T3,
    const int* __restrict__ flag) {
  bool f = flag[0] != 0;
  int k = blockIdx.x, n = threadIdx.x, y = blockIdx.y;
  const void* W = (y == 0) ? W0 : (y == 1) ? W1 : (y == 2) ? W2 : W3;
  const void* Wp = (y < 2) ? Wp1 : Wp2;
  __bf16* T = (y == 0) ? T0 : (y == 1) ? T1 : (y == 2) ? T2 : T3;
  float s = 0.f;
#pragma unroll 4
  for (int j = 0; j < CDIM; ++j)
    s += ld1(W, (size_t)k * CDIM + j, f) * ld1(Wp, (size_t)j * CDIM + n, f);
  T[n * CDIM + k] = (__bf16)s;
}

__global__ void prep_misc_kernel(const void* __restrict__ Wpost,
                                 const void* __restrict__ bpost,
                                 const void* __restrict__ bp1,
                                 const void* __restrict__ bp2,
                                 float* __restrict__ wsum,
                                 float* __restrict__ bpf1,
                                 float* __restrict__ bpf2,
                                 const int* __restrict__ flag) {
  bool f = flag[0] != 0;
  int t = threadIdx.x;  // 128
  wsum[t] = ld1(Wpost, (size_t)t * 2, f) + ld1(Wpost, (size_t)t * 2 + 1, f);
  bpf1[t] = ld1(bp1, t, f);
  bpf2[t] = ld1(bp2, t, f);
  if (t == 0) wsum[CDIM] = ld1(bpost, 0, f) + ld1(bpost, 1, f);
}

// ---- block-cooperative gather(seg-mean) + dual-GEMM + blend (shadow path) ---
// One 256-thread block per 16-row tile. Wave w sums edge-quarter w of each
// row; partials reduce via padded LDS; wave w then computes output col-tiles
// {2w, 2w+1} via MFMA. out = blend(past, mean @ WtN^T + X @ WtS^T + bias).
// Phase C stages the C-tile in LDS and writes out/shadow (+past blend read)
// fully coalesced (fixes round-5's 4x WRITE amplification).
// mfma_f32_16x16x32_bf16 layouts (m89/m91-verified):
//   A: lane = A[m=lane&15][k=(lane>>4)*8+j+ks*32]; B from Wt[n][k] storage;
//   C/D: col=lane&15, row=(lane>>4)*4+reg.
template <bool HAS_BIAS>
__global__ __launch_bounds__(256, 4) void gather_gemm_coop(
    const int* __restrict__ off, const int* __restrict__ perm,
    const __bf16* __restrict__ feat, const __bf16* __restrict__ X,
    const __bf16* __restrict__ WtN, const __bf16* __restrict__ WtS,
    const float* __restrict__ bias, const void* __restrict__ past,
    __bf16* __restrict__ shadow_out, const int* __restrict__ snapp,
    const int* __restrict__ flag, void* __restrict__ outb, long outoff,
    int nRowTiles) {
  __shared__ float lds[4][16][132];  // phase A/B partials; phase C reuses
  float* ldsOut = &lds[0][0][0];     // [16][132] f32 C-tile stage (8.4 KB)
  bool f32o = (flag[0] != 0);
  bool blend = (snapp[0] != 0);
  int t = threadIdx.x;
  int w = t >> 6, lane = t & 63, ln = lane & 15, q = lane >> 4;
  int cq = q * 8;
  for (int rt = blockIdx.x; rt < nRowTiles; rt += gridDim.x) {
    int row = rt * 16 + ln;
    int beg = off[row], end = off[row + 1];
    int cnt = end - beg;
    int myBeg = beg + ((cnt * w) >> 2);
    int myEnd = beg + ((cnt * (w + 1)) >> 2);
    // ---- phase A: per-wave partial edge sums (quarter of each row) ----
    float s[4][8];
#pragma unroll
    for (int a = 0; a < 4; ++a)
#pragma unroll
      for (int j = 0; j < 8; ++j) s[a][j] = 0.f;
    {
      const __bf16* fb = feat + cq;
      int i = myBeg;
      for (; i + 1 < myEnd; i += 2) {
        const __bf16* fp0 = fb + (size_t)perm[i] * CDIM;
        const __bf16* fp1 = fb + (size_t)perm[i + 1] * CDIM;
        bf16x8 v0[4], v1[4];
#pragma unroll
        for (int ks = 0; ks < 4; ++ks) v0[ks] = *(const bf16x8*)(fp0 + ks * 32);
#pragma unroll
        for (int ks = 0; ks < 4; ++ks) v1[ks] = *(const bf16x8*)(fp1 + ks * 32);
#pragma unroll
        for (int ks = 0; ks < 4; ++ks)
#pragma unroll
          for (int j = 0; j < 8; ++j)
            s[ks][j] += (float)v0[ks][j] + (float)v1[ks][j];
      }
      if (i < myEnd) {
        const __bf16* fp = fb + (size_t)perm[i] * CDIM;
#pragma unroll
        for (int ks = 0; ks < 4; ++ks) {
          bf16x8 v = *(const bf16x8*)(fp + ks * 32);
#pragma unroll
          for (int j = 0; j < 8; ++j) s[ks][j] += (float)v[j];
        }
      }
    }
#pragma unroll
    for (int ks = 0; ks < 4; ++ks) {
      *(f32x4*)&lds[w][ln][cq + ks * 32] =
          (f32x4){s[ks][0], s[ks][1], s[ks][2], s[ks][3]};
      *(f32x4*)&lds[w][ln][cq + ks * 32 + 4] =
          (f32x4){s[ks][4], s[ks][5], s[ks][6], s[ks][7]};
    }
    __syncthreads();
    // ---- phase B: reduce partials, build fragments, MFMA 2 col-tiles ----
    float rc = 1.0f / fmaxf((float)cnt, 1.0f);
    bf16x8 a1[4], a2[4];
#pragma unroll
    for (int ks = 0; ks < 4; ++ks) {
      f32x4 lo = (f32x4){0.f, 0.f, 0.f, 0.f};
      f32x4 hi = (f32x4){0.f, 0.f, 0.f, 0.f};
#pragma unroll
      for (int w2 = 0; w2 < 4; ++w2) {
        const float* p = &lds[w2][ln][cq + ks * 32];
        lo += *(const f32x4*)p;
        hi += *(const f32x4*)(p + 4);
      }
      bf16x8 t1;
#pragma unroll
      for (int j = 0; j < 4; ++j) {
        t1[j] = (__bf16)(lo[j] * rc);
        t1[4 + j] = (__bf16)(hi[j] * rc);
      }
      a1[ks] = t1;
      a2[ks] = *(const bf16x8*)(X + (size_t)row * CDIM + cq + ks * 32);
    }
    f32x4 d0 = (f32x4){0.f, 0.f, 0.f, 0.f};
    f32x4 d1 = (f32x4){0.f, 0.f, 0.f, 0.f};
    const __bf16* bn0 = WtN + (size_t)((2 * w) * 16 + ln) * CDIM + cq;
    const __bf16* bs0 = WtS + (size_t)((2 * w) * 16 + ln) * CDIM + cq;
#pragma unroll
    for (int ks = 0; ks < 4; ++ks) {
      d0 = __builtin_amdgcn_mfma_f32_16x16x32_bf16(
          a1[ks], *(const bf16x8*)(bn0 + ks * 32), d0, 0, 0, 0);
      d0 = __builtin_amdgcn_mfma_f32_16x16x32_bf16(
          a2[ks], *(const bf16x8*)(bs0 + ks * 32), d0, 0, 0, 0);
      d1 = __builtin_amdgcn_mfma_f32_16x16x32_bf16(
          a1[ks], *(const bf16x8*)(bn0 + 16 * CDIM + ks * 32), d1, 0, 0, 0);
      d1 = __builtin_amdgcn_mfma_f32_16x16x32_bf16(
          a2[ks], *(const bf16x8*)(bs0 + 16 * CDIM + ks * 32), d1, 0, 0, 0);
    }
    // ---- phase C: stage C-tile (+bias) in LDS, then coalesced epilogue ----
    __syncthreads();  // all phase-B LDS reads done before ldsOut overwrite
#pragma unroll
    for (int p = 0; p < 2; ++p) {
      f32x4 dd = p ? d1 : d0;
      int col = (2 * w + p) * 16 + ln;
      float bv = HAS_BIAS ? bias[col] : 0.0f;
#pragma unroll
      for (int r = 0; r < 4; ++r)
        ldsOut[(q * 4 + r) * 132 + col] = dd[r] + bv;  // 2-way bank: free
    }
    __syncthreads();
    {
      // 256 threads cover 16x128: thread t -> row t>>4, cols (t&15)*8..+7
      int orow16 = t >> 4, c0 = (t & 15) * 8;
      long orow = (long)rt * 16 + orow16;
      const float* lp = ldsOut + orow16 * 132 + c0;
      f32x4 v0 = *(const f32x4*)lp;
      f32x4 v1 = *(const f32x4*)(lp + 4);
      if (blend) {
        if (f32o) {
          const float* pp = (const float*)past + orow * CDIM + c0;
          f32x4 p0 = *(const f32x4*)pp;
          f32x4 p1 = *(const f32x4*)(pp + 4);
#pragma unroll
          for (int j = 0; j < 4; ++j) {
            v0[j] = 0.05f * p0[j] + 0.95f * v0[j];
            v1[j] = 0.05f * p1[j] + 0.95f * v1[j];
          }
        } else {
          bf16x8 pb =
              *(const bf16x8*)((const __bf16*)past + orow * CDIM + c0);
#pragma unroll
          for (int j = 0; j < 4; ++j) {
            v0[j] = 0.05f * (float)pb[j] + 0.95f * v0[j];
            v1[j] = 0.05f * (float)pb[4 + j] + 0.95f * v1[j];
          }
        }
      }
      if (shadow_out) {
        bf16x8 sh;
#pragma unroll
        for (int j = 0; j < 4; ++j) {
          sh[j] = (__bf16)v0[j];
          sh[4 + j] = (__bf16)v1[j];
        }
        *(bf16x8*)(shadow_out + orow * CDIM + c0) = sh;
      }
      if (f32o) {
        float* op = (float*)outb + outoff + orow * CDIM + c0;
        *(f32x4*)op = v0;
        *(f32x4*)(op + 4) = v1;
      } else {
        bf16x8 ob;
#pragma unroll
        for (int j = 0; j < 4; ++j) {
          ob[j] = (__bf16)v0[j];
          ob[4 + j] = (__bf16)v1[j];
        }
        *(bf16x8*)((__bf16*)outb + outoff + orow * CDIM + c0) = ob;
      }
    }
    __syncthreads();  // lds reused next rt iteration (exact grid: runs once)
  }
}

// ---- fallback per-wave fused kernel (verified round-3 path, f32 gathers) ----
template <bool HAS_BIAS>
__global__ __launch_bounds__(256) void gather_gemm_kernel(
    const int* __restrict__ off, const int* __restrict__ perm,
    const void* __restrict__ featb, long featoff,
    const void* __restrict__ Xb, long xoff,
    const __bf16* __restrict__ WtN, const __bf16* __restrict__ WtS,
    const float* __restrict__ bias, const void* __restrict__ past,
    const int* __restrict__ snapp, const int* __restrict__ flag,
    void* __restrict__ outb, long outoff, int nRowTiles) {
  bool f32 = (flag[0] != 0);
  bool blend = (snapp[0] != 0);
  int lane = threadIdx.x & 63;
  int ln = lane & 15, q = lane >> 4;
  int wave = blockIdx.x * 4 + (threadIdx.x >> 6);
  int nW = gridDim.x * 4;
  size_t cq = (size_t)q * 8;
  for (int rt = wave; rt < nRowTiles; rt += nW) {
    int row = rt * 16 + ln;
    int beg = off[row], end = off[row + 1];
    float s[4][8];
#pragma unroll
    for (int a = 0; a < 4; ++a)
#pragma unroll
      for (int j = 0; j < 8; ++j) s[a][j] = 0.f;
    if (f32) {
      const float* fb = (const float*)featb + featoff + cq;
      for (int i = beg; i < end; ++i) {
        const float* fp = fb + (size_t)perm[i] * CDIM;
#pragma unroll
        for (int ks = 0; ks < 4; ++ks) {
          f32x4 lo = *(const f32x4*)(fp + ks * 32);
          f32x4 hi = *(const f32x4*)(fp + ks * 32 + 4);
#pragma unroll
          for (int j = 0; j < 4; ++j) {
            s[ks][j] += lo[j];
            s[ks][4 + j] += hi[j];
          }
        }
      }
    } else {
      const __bf16* fb = (const __bf16*)featb + featoff + cq;
      for (int i = beg; i < end; ++i) {
        const __bf16* fp = fb + (size_t)perm[i] * CDIM;
#pragma unroll
        for (int ks = 0; ks < 4; ++ks) {
          bf16x8 v = *(const bf16x8*)(fp + ks * 32);
#pragma unroll
          for (int j = 0; j < 8; ++j) s[ks][j] += (float)v[j];
        }
      }
    }
    float rc = 1.0f / fmaxf((float)(end - beg), 1.0f);
    bf16x8 a1[4], a2[4];
    size_t xb = (size_t)row * CDIM + cq;
#pragma unroll
    for (int ks = 0; ks < 4; ++ks) {
      bf16x8 t1, t2;
      if (f32) {
        const float* xp = (const float*)Xb + xoff + xb + ks * 32;
        f32x4 lo = *(const f32x4*)xp;
        f32x4 hi = *(const f32x4*)(xp + 4);
#pragma unroll
        for (int j = 0; j < 4; ++j) {
          t2[j] = (__bf16)lo[j];
          t2[4 + j] = (__bf16)hi[j];
        }
      } else {
        t2 = *(const bf16x8*)((const __bf16*)Xb + xoff + xb + ks * 32);
      }
#pragma unroll
      for (int j = 0; j < 8; ++j) t1[j] = (__bf16)(s[ks][j] * rc);
      a1[ks] = t1;
      a2[ks] = t2;
    }
    f32x4 d[8];
#pragma unroll
    for (int ct = 0; ct < 8; ++ct) d[ct] = (f32x4){0.f, 0.f, 0.f, 0.f};
#pragma unroll
    for (int ct = 0; ct < 8; ++ct) {
      const __bf16* bn = WtN + (size_t)(ct * 16 + ln) * CDIM + q * 8;
      const __bf16* bs = WtS + (size_t)(ct * 16 + ln) * CDIM + q * 8;
#pragma unroll
      for (int ks = 0; ks < 4; ++ks) {
        d[ct] = __builtin_amdgcn_mfma_f32_16x16x32_bf16(
            a1[ks], *(const bf16x8*)(bn + ks * 32), d[ct], 0, 0, 0);
        d[ct] = __builtin_amdgcn_mfma_f32_16x16x32_bf16(
            a2[ks], *(const bf16x8*)(bs + ks * 32), d[ct], 0, 0, 0);
      }
    }
#pragma unroll
    for (int ct = 0; ct < 8; ++ct) {
      int col = ct * 16 + ln;
      float bv = HAS_BIAS ? bias[col] : 0.0f;
#pragma unroll
      for (int r = 0; r < 4; ++r) {
        long orow = rt * 16 + q * 4 + r;
        float v = d[ct][r] + bv;
        if (blend)
          v = 0.05f * ld1(past, (size_t)orow * CDIM + col, f32) + 0.95f * v;
        size_t oidx = (size_t)(outoff + orow * CDIM + col);
        if (f32)
          ((float*)outb)[oidx] = v;
        else
          ((__bf16*)outb)[oidx] = (__bf16)v;
      }
    }
  }
}

// ---- link scoring -----------------------------------------------------------
__global__ __launch_bounds__(256) void score_kernel(
    void* __restrict__ outb, const int* __restrict__ ls,
    const int* __restrict__ ld, const float* __restrict__ wsum,
    const int* __restrict__ flag) {
  bool f32 = (flag[0] != 0);
  int t = blockIdx.x * blockDim.x + threadIdx.x;
  int l = t >> 4;
  if (l >= LBL) return;
  size_t c8 = (size_t)(t & 15) << 3;
  float av[8], bv[8];
  if (f32) {
    const float* u = (const float*)outb + OFF_C2U + (size_t)ls[l] * CDIM + c8;
    const float* v = (const float*)outb + OFF_C2I + (size_t)ld[l] * CDIM + c8;
    f32x4 u0 = *(const f32x4*)u, u1 = *(const f32x4*)(u + 4);
    f32x4 v0 = *(const f32x4*)v, v1 = *(const f32x4*)(v + 4);
#pragma unroll
    for (int j = 0; j < 4; ++j) {
      av[j] = u0[j]; av[4 + j] = u1[j];
      bv[j] = v0[j]; bv[4 + j] = v1[j];
    }
  } else {
    bf16x8 a = *(const bf16x8*)((const __bf16*)outb + OFF_C2U +
                                (size_t)ls[l] * CDIM + c8);
    bf16x8 b = *(const bf16x8*)((const __bf16*)outb + OFF_C2I +
                                (size_t)ld[l] * CDIM + c8);
#pragma unroll
    for (int j = 0; j < 8; ++j) { av[j] = (float)a[j]; bv[j] = (float)b[j]; }
  }
  float p = 0.f;
#pragma unroll
  for (int j = 0; j < 8; ++j) p += av[j] * bv[j] * wsum[c8 + j];
  p += __shfl_xor(p, 1, 16);
  p += __shfl_xor(p, 2, 16);
  p += __shfl_xor(p, 4, 16);
  p += __shfl_xor(p, 8, 16);
  if ((t & 15) == 0) {
    float h = p + wsum[CDIM];
    if (f32)
      ((float*)outb)[l] = h;
    else
      ((__bf16*)outb)[l] = (__bf16)h;
  }
}

// ---------------------------------------------------------------------------
extern "C" void kernel_launch(void* const* d_in, const int* in_sizes, int n_in,
                              void* d_out, int out_size, void* d_ws,
                              size_t ws_size, hipStream_t stream) {
  const void* x_user = d_in[0];
  const void* x_item = d_in[1];
  const void* past1_user = d_in[2];
  const void* past1_item = d_in[3];
  const void* past2_user = d_in[4];
  const void* past2_item = d_in[5];
  const void* W1ui_n = d_in[6];
  const void* W1ui_s = d_in[7];
  const void* W1iu_n = d_in[8];
  const void* W1iu_s = d_in[9];
  const void* Wp1 = d_in[10];
  const void* bp1 = d_in[11];
  const void* W2ui_n = d_in[15];
  const void* W2ui_s = d_in[16];
  const void* W2iu_n = d_in[17];
  const void* W2iu_s = d_in[18];
  const void* Wp2 = d_in[19];
  const void* bp2 = d_in[20];
  const void* Wpost = d_in[24];
  const void* bpost = d_in[25];
  const int* src_ui = (const int*)d_in[26];
  const int* dst_ui = (const int*)d_in[27];
  const int* src_iu = (const int*)d_in[28];
  const int* dst_iu = (const int*)d_in[29];
  const int* lbl_src = (const int*)d_in[30];
  const int* lbl_dst = (const int*)d_in[31];
  const int* snap = (const int*)d_in[32];

  // ---- workspace carve, 256B-aligned sections ----
  size_t wo = 0;
  auto alloc = [&](size_t bytes) -> char* {
    char* p = (char*)d_ws + wo;
    wo += (bytes + 255) & ~(size_t)255;
    return p;
  };
  int* cntI = (int*)alloc(NITEM * 4);
  int* cntU = (int*)alloc(NUSER * 4);
  int* flag = (int*)alloc(256);
  size_t zeroBytes = wo;  // cntI + cntU + flag zeroed in one memset
  int* offI = (int*)alloc((NITEM + 1) * 4);
  int* offU = (int*)alloc((NUSER + 1) * 4);
  int* curI = (int*)alloc(NITEM * 4);
  int* curU = (int*)alloc(NUSER * 4);
  int* permI = (int*)alloc(EDGES * 4);
  int* permU = (int*)alloc(EDGES * 4);
  float* wsum = (float*)alloc(256 * 4);
  float* bpf1 = (float*)alloc(CDIM * 4);
  float* bpf2 = (float*)alloc(CDIM * 4);
  __bf16* wt0 = (__bf16*)alloc(8 * CDIM * CDIM * 2);
  __bf16* Wt[8];
  for (int i = 0; i < 8; ++i) Wt[i] = wt0 + (size_t)i * CDIM * CDIM;
  // bf16 shadow tables (gather sources). Used only if they fit.
  __bf16* xu_sh = (__bf16*)alloc((size_t)NUSER * CDIM * 2);
  __bf16* xi_sh = (__bf16*)alloc((size_t)NITEM * CDIM * 2);
  __bf16* c1u_sh = (__bf16*)alloc((size_t)NUSER * CDIM * 2);
  __bf16* c1i_sh = (__bf16*)alloc((size_t)NITEM * CDIM * 2);
  bool useShadow = (wo <= ws_size);
  // partition-path buffers (+~8.3 MB). Used only if they also fit.
  int* HI = (int*)alloc((size_t)(NBI * NBLK + 1) * 4);
  int* HU = (int*)alloc((size_t)(NBU * NBLK + 1) * 4);
  int* HIoff = (int*)alloc((size_t)(NBI * NBLK + 1) * 4);
  int* HUoff = (int*)alloc((size_t)(NBU * NBLK + 1) * 4);
  int* pairsI = (int*)alloc((size_t)EDGES * 4);
  int* pairsU = (int*)alloc((size_t)EDGES * 4);
  bool usePart = (wo <= ws_size);

  const int EB = (EDGES + 255) / 256;
  const int T_ITEM = NITEM / 16;  // 3125 tiles
  const int T_USER = NUSER / 16;  // 6250 tiles

  hipMemsetAsync(d_ws, 0, zeroBytes, stream);
  probe_dtype_kernel<<<1, 256, 0, stream>>>((const unsigned short*)x_user,
                                            flag);

  // CSR build (shared by both layers)
  if (usePart) {
    partA_kernel<<<dim3(NBLK, 2), 256, 0, stream>>>(dst_ui, dst_iu, cntI,
                                                    cntU, HI, HU);
    scan4_kernel<<<4, 1024, 0, stream>>>(cntI, offI, curI, NITEM, cntU, offU,
                                         curU, NUSER, HI, HIoff, NBI * NBLK,
                                         HU, HUoff, NBU * NBLK);
    partC_kernel<<<dim3(NBLK, 2), 256, 0, stream>>>(
        src_ui, dst_ui, src_iu, dst_iu, HIoff, HUoff, pairsI, pairsU);
    bucketB_kernel<<<dim3(NBU, 2), 256, 0, stream>>>(
        HIoff, HUoff, pairsI, pairsU, offI, offU, permI, permU);
  } else {
    hist_kernel<<<EB, 256, 0, stream>>>(dst_ui, dst_iu, cntI, cntU);
    scan4_kernel<<<2, 1024, 0, stream>>>(cntI, offI, curI, NITEM, cntU, offU,
                                         curU, NUSER, nullptr, nullptr, 0,
                                         nullptr, nullptr, 0);
    bucket_kernel<<<EB, 256, 0, stream>>>(src_ui, dst_ui, src_iu, dst_iu,
                                          curI, curU, permI, permU);
  }

  // weight prep: Wt0/1 = W1ui_{n,s}^T, Wt4/5 = W2ui_{n,s}^T,
  //              Wt2/3 = (W1iu_{n,s}@Wp1)^T, Wt6/7 = (W2iu_{n,s}@Wp2)^T
  prep_transpose_kernel<<<dim3(CDIM, 4), CDIM, 0, stream>>>(
      W1ui_n, W1ui_s, W2ui_n, W2ui_s, Wt[0], Wt[1], Wt[4], Wt[5], flag);
  prep_combine_kernel<<<dim3(CDIM, 4), CDIM, 0, stream>>>(
      W1iu_n, W1iu_s, W2iu_n, W2iu_s, Wp1, Wp2, Wt[2], Wt[3], Wt[6], Wt[7],
      flag);
  prep_misc_kernel<<<1, CDIM, 0, stream>>>(Wpost, bpost, bp1, bp2, wsum, bpf1,
                                           bpf2, flag);

  if (useShadow) {
    // bf16 shadows of the gathered tables: halves gather traffic.
    convert_bf16_kernel<<<(NUSER * CDIM) / 2048, 256, 0, stream>>>(
        x_user, xu_sh, (long)NUSER * CDIM, flag);
    convert_bf16_kernel<<<(NITEM * CDIM) / 2048, 256, 0, stream>>>(
        x_item, xi_sh, (long)NITEM * CDIM, flag);
    // layer 1 (writes bf16 shadows of cur1 for layer-2 gathers)
    gather_gemm_coop<false><<<T_ITEM, 256, 0, stream>>>(
        offI, permI, xu_sh, xi_sh, Wt[0], Wt[1], nullptr, past1_item, c1i_sh,
        snap, flag, d_out, OFF_C1I, T_ITEM);
    gather_gemm_coop<true><<<T_USER, 256, 0, stream>>>(
        offU, permU, xi_sh, xu_sh, Wt[2], Wt[3], bpf1, past1_user, c1u_sh,
        snap, flag, d_out, OFF_C1U, T_USER);
    // layer 2 (gathers bf16 shadows; no shadow output needed)
    gather_gemm_coop<false><<<T_ITEM, 256, 0, stream>>>(
        offI, permI, c1u_sh, c1i_sh, Wt[4], Wt[5], nullptr, past2_item,
        nullptr, snap, flag, d_out, OFF_C2I, T_ITEM);
    gather_gemm_coop<true><<<T_USER, 256, 0, stream>>>(
        offU, permU, c1i_sh, c1u_sh, Wt[6], Wt[7], bpf2, past2_user, nullptr,
        snap, flag, d_out, OFF_C2U, T_USER);
  } else {
    // fallback: previously-verified dual-dtype per-wave path
    const int G_ITEM = (T_ITEM + 3) / 4;
    const int G_USER = (T_USER + 3) / 4;
    gather_gemm_kernel<false><<<G_ITEM, 256, 0, stream>>>(
        offI, permI, x_user, 0, x_item, 0, Wt[0], Wt[1], nullptr, past1_item,
        snap, flag, d_out, OFF_C1I, T_ITEM);
    gather_gemm_kernel<true><<<G_USER, 256, 0, stream>>>(
        offU, permU, x_item, 0, x_user, 0, Wt[2], Wt[3], bpf1, past1_user,
        snap, flag, d_out, OFF_C1U, T_USER);
    gather_gemm_kernel<false><<<G_ITEM, 256, 0, stream>>>(
        offI, permI, d_out, OFF_C1U, d_out, OFF_C1I, Wt[4], Wt[5], nullptr,
        past2_item, snap, flag, d_out, OFF_C2I, T_ITEM);
    gather_gemm_kernel<true><<<G_USER, 256, 0, stream>>>(
        offU, permU, d_out, OFF_C1I, d_out, OFF_C1U, Wt[6], Wt[7], bpf2,
        past2_user, snap, flag, d_out, OFF_C2U, T_USER);
  }

  // scoring (reads full-precision cur2 from d_out)
  score_kernel<<<(LBL * 16) / 256, 256, 0, stream>>>(d_out, lbl_src, lbl_dst,
                                                     wsum, flag);
}